// Round 1
// baseline (6773.941 us; speedup 1.0000x reference)
//
#include <hip/hip_runtime.h>
#include <hip/hip_bf16.h>

#define NN   50000
#define CIN  128
#define CH   256
#define COUT 128
#define NE   640000
#define NPE  500000
#define FEPS 1e-5f

__global__ void k_zero(float* p, int n4) {
    int i = blockIdx.x * blockDim.x + threadIdx.x;
    float4 z = {0.f, 0.f, 0.f, 0.f};
    for (; i < n4; i += gridDim.x * blockDim.x) ((float4*)p)[i] = z;
}

__global__ void k_count(const int* __restrict__ dst, float* __restrict__ cnt) {
    int e = blockIdx.x * blockDim.x + threadIdx.x;
    if (e < NE) atomicAdd(&cnt[dst[e]], 1.0f);
}

template <int C>
__global__ void k_scatter(const int* __restrict__ src, const int* __restrict__ dst,
                          const float* __restrict__ feat, float* __restrict__ agg) {
    const int PER = C / 4;
    int i = blockIdx.x * blockDim.x + threadIdx.x;
    if (i >= NE * PER) return;
    int e  = i / PER;
    int c4 = (i % PER) * 4;
    int s = src[e], d = dst[e];
    float4 v = *(const float4*)(feat + (size_t)s * C + c4);
    float* o = agg + (size_t)d * C + c4;
    atomicAdd(o + 0, v.x);
    atomicAdd(o + 1, v.y);
    atomicAdd(o + 2, v.z);
    atomicAdd(o + 3, v.w);
}

// SAGE layer 1: h = relu(bn(mean @ W1l^T + x @ W1r^T + b1)); tile = 32 nodes
__global__ __launch_bounds__(256) void k_sage1(
    const float* __restrict__ x, const float* __restrict__ agg, const float* __restrict__ cnt,
    const float* __restrict__ Wl, const float* __restrict__ Wr, const float* __restrict__ b,
    const float* __restrict__ bg, const float* __restrict__ bb,
    const float* __restrict__ bm, const float* __restrict__ bv,
    float* __restrict__ h) {
    __shared__ float xs[32 * CIN];
    __shared__ float ms[32 * CIN];
    int t = threadIdx.x;
    int n0 = blockIdx.x * 32;
    for (int j = 0; j < 4; ++j) {
        int idx = t + j * 256;            // 0..1023 : 32 nodes x 32 float4
        int node = idx >> 5, k4 = (idx & 31) << 2;
        int gn = n0 + node;
        float4 xv = {0,0,0,0}, mv = {0,0,0,0};
        if (gn < NN) {
            xv = *(const float4*)(x + (size_t)gn * CIN + k4);
            mv = *(const float4*)(agg + (size_t)gn * CIN + k4);
            float inv = 1.0f / fmaxf(cnt[gn], 1.0f);
            mv.x *= inv; mv.y *= inv; mv.z *= inv; mv.w *= inv;
        }
        *(float4*)(xs + node * CIN + k4) = xv;
        *(float4*)(ms + node * CIN + k4) = mv;
    }
    __syncthreads();
    int c = t;                              // 0..255 = output channel
    float acc[32];
#pragma unroll
    for (int i2 = 0; i2 < 32; ++i2) acc[i2] = 0.f;
    for (int k0 = 0; k0 < CIN; k0 += 4) {
        float4 wl = *(const float4*)(Wl + (size_t)c * CIN + k0);
        float4 wr = *(const float4*)(Wr + (size_t)c * CIN + k0);
#pragma unroll
        for (int mm = 0; mm < 32; ++mm) {
            float4 xv = *(const float4*)(xs + mm * CIN + k0);
            float4 mv = *(const float4*)(ms + mm * CIN + k0);
            acc[mm] += mv.x * wl.x + mv.y * wl.y + mv.z * wl.z + mv.w * wl.w
                     + xv.x * wr.x + xv.y * wr.y + xv.z * wr.z + xv.w * wr.w;
        }
    }
    float sc = bg[c] * rsqrtf(bv[c] + FEPS);
    float sh = bb[c] - bm[c] * sc;
    float bias = b[c];
    for (int mm = 0; mm < 32; ++mm) {
        int gn = n0 + mm;
        if (gn < NN) {
            float val = (acc[mm] + bias) * sc + sh;
            h[(size_t)gn * CH + c] = fmaxf(val, 0.f);
        }
    }
}

// SAGE layer 2: z = mean2 @ W2l^T + h @ W2r^T + b2 ; tile = 24 nodes
__global__ __launch_bounds__(256) void k_sage2(
    const float* __restrict__ h, const float* __restrict__ agg, const float* __restrict__ cnt,
    const float* __restrict__ Wl, const float* __restrict__ Wr, const float* __restrict__ b,
    float* __restrict__ z) {
    __shared__ float hs[24 * CH];
    __shared__ float ms[24 * CH];
    int t = threadIdx.x;
    int n0 = blockIdx.x * 24;
    for (int j = 0; j < 6; ++j) {
        int idx = t + j * 256;            // 0..1535 : 24 nodes x 64 float4
        int node = idx >> 6, k4 = (idx & 63) << 2;
        int gn = n0 + node;
        float4 hv = {0,0,0,0}, mv = {0,0,0,0};
        if (gn < NN) {
            hv = *(const float4*)(h + (size_t)gn * CH + k4);
            mv = *(const float4*)(agg + (size_t)gn * CH + k4);
            float inv = 1.0f / fmaxf(cnt[gn], 1.0f);
            mv.x *= inv; mv.y *= inv; mv.z *= inv; mv.w *= inv;
        }
        *(float4*)(hs + node * CH + k4) = hv;
        *(float4*)(ms + node * CH + k4) = mv;
    }
    __syncthreads();
    int c = t & 127, mg = t >> 7;          // 2 groups x 12 nodes
    float acc[12];
#pragma unroll
    for (int i2 = 0; i2 < 12; ++i2) acc[i2] = 0.f;
    for (int k0 = 0; k0 < CH; k0 += 4) {
        float4 wl = *(const float4*)(Wl + (size_t)c * CH + k0);
        float4 wr = *(const float4*)(Wr + (size_t)c * CH + k0);
#pragma unroll
        for (int mm = 0; mm < 12; ++mm) {
            int node = mg * 12 + mm;
            float4 hv = *(const float4*)(hs + node * CH + k0);
            float4 mv = *(const float4*)(ms + node * CH + k0);
            acc[mm] += mv.x * wl.x + mv.y * wl.y + mv.z * wl.z + mv.w * wl.w
                     + hv.x * wr.x + hv.y * wr.y + hv.z * wr.z + hv.w * wr.w;
        }
    }
    float bias = b[c];
    for (int mm = 0; mm < 12; ++mm) {
        int gn = n0 + mg * 12 + mm;
        if (gn < NN) z[(size_t)gn * COUT + c] = acc[mm] + bias;
    }
}

// fused link-predictor MLP: 16 edges / block
__global__ __launch_bounds__(256) void k_mlp(
    const float* __restrict__ z, const int* __restrict__ pu, const int* __restrict__ pv,
    const float* __restrict__ W1, const float* __restrict__ b1,
    const float* __restrict__ g1, const float* __restrict__ be1,
    const float* __restrict__ m1, const float* __restrict__ v1,
    const float* __restrict__ W2, const float* __restrict__ b2,
    const float* __restrict__ g2, const float* __restrict__ be2,
    const float* __restrict__ m2, const float* __restrict__ v2,
    const float* __restrict__ W3, const float* __restrict__ b3,
    float* __restrict__ out) {
    __shared__ float q[16 * 256];
    __shared__ float q1[16 * 256];
    __shared__ float q2[16 * 128];
    int t = threadIdx.x;
    int e0 = blockIdx.x * 16;
    // gather endpoint embeddings: 16 edges x 64 float4 (PE % 16 == 0, no guard)
    for (int j = 0; j < 4; ++j) {
        int idx = t + j * 256;
        int e = idx >> 6, f = idx & 63;
        int ge = e0 + e;
        int node = (f < 32) ? pu[ge] : pv[ge];
        float4 val = *(const float4*)(z + (size_t)node * COUT + ((f & 31) << 2));
        *(float4*)(q + e * 256 + (f << 2)) = val;
    }
    __syncthreads();
    {   // layer 1: 256->256, c = t
        int c = t;
        float acc[16];
#pragma unroll
        for (int i2 = 0; i2 < 16; ++i2) acc[i2] = 0.f;
        for (int k0 = 0; k0 < 256; k0 += 4) {
            float4 w = *(const float4*)(W1 + (size_t)c * 256 + k0);
#pragma unroll
            for (int e = 0; e < 16; ++e) {
                float4 qv = *(const float4*)(q + e * 256 + k0);
                acc[e] += qv.x * w.x + qv.y * w.y + qv.z * w.z + qv.w * w.w;
            }
        }
        float sc = g1[c] * rsqrtf(v1[c] + FEPS);
        float sh = be1[c] - m1[c] * sc;
        float bias = b1[c];
#pragma unroll
        for (int e = 0; e < 16; ++e)
            q1[e * 256 + c] = fmaxf((acc[e] + bias) * sc + sh, 0.f);
    }
    __syncthreads();
    {   // layer 2: 256->128, c = t&127, half the edges per thread-group
        int c = t & 127, eg = t >> 7;
        float acc[8];
#pragma unroll
        for (int i2 = 0; i2 < 8; ++i2) acc[i2] = 0.f;
        for (int k0 = 0; k0 < 256; k0 += 4) {
            float4 w = *(const float4*)(W2 + (size_t)c * 256 + k0);
#pragma unroll
            for (int e = 0; e < 8; ++e) {
                float4 qv = *(const float4*)(q1 + (eg * 8 + e) * 256 + k0);
                acc[e] += qv.x * w.x + qv.y * w.y + qv.z * w.z + qv.w * w.w;
            }
        }
        float sc = g2[c] * rsqrtf(v2[c] + FEPS);
        float sh = be2[c] - m2[c] * sc;
        float bias = b2[c];
#pragma unroll
        for (int e = 0; e < 8; ++e)
            q2[(eg * 8 + e) * 128 + c] = fmaxf((acc[e] + bias) * sc + sh, 0.f);
    }
    __syncthreads();
    {   // layer 3: 128->1, 16 threads per edge
        int e = t >> 4, j = t & 15;
        float p = 0.f;
#pragma unroll
        for (int k = 0; k < 8; ++k)
            p += q2[e * 128 + j * 8 + k] * W3[j * 8 + k];
        p += __shfl_down(p, 8, 16);
        p += __shfl_down(p, 4, 16);
        p += __shfl_down(p, 2, 16);
        p += __shfl_down(p, 1, 16);
        if (j == 0) out[e0 + e] = p + b3[0];
    }
}

extern "C" void kernel_launch(void* const* d_in, const int* in_sizes, int n_in,
                              void* d_out, int out_size, void* d_ws, size_t ws_size,
                              hipStream_t stream) {
    const float* x    = (const float*)d_in[0];
    const int*   ei   = (const int*)d_in[1];
    const int*   pei  = (const int*)d_in[2];
    const float* W1l  = (const float*)d_in[3];
    const float* W1r  = (const float*)d_in[4];
    const float* b1   = (const float*)d_in[5];
    const float* bn1g = (const float*)d_in[6];
    const float* bn1b = (const float*)d_in[7];
    const float* bn1m = (const float*)d_in[8];
    const float* bn1v = (const float*)d_in[9];
    const float* W2l  = (const float*)d_in[10];
    const float* W2r  = (const float*)d_in[11];
    const float* b2   = (const float*)d_in[12];
    const float* pW1  = (const float*)d_in[13];
    const float* pb1  = (const float*)d_in[14];
    const float* pg1  = (const float*)d_in[15];
    const float* pbb1 = (const float*)d_in[16];
    const float* pm1  = (const float*)d_in[17];
    const float* pv1  = (const float*)d_in[18];
    const float* pW2  = (const float*)d_in[19];
    const float* pb2  = (const float*)d_in[20];
    const float* pg2  = (const float*)d_in[21];
    const float* pbb2 = (const float*)d_in[22];
    const float* pm2  = (const float*)d_in[23];
    const float* pv2  = (const float*)d_in[24];
    const float* pW3  = (const float*)d_in[25];
    const float* pb3  = (const float*)d_in[26];
    float* out = (float*)d_out;

    const int* src = ei;            // edge_index[0]
    const int* dst = ei + NE;       // edge_index[1]
    const int* pu  = pei;           // pred_edge_index[0]
    const int* pv  = pei + NPE;     // pred_edge_index[1]

    float* ws  = (float*)d_ws;
    float* cnt = ws;                          // N floats
    float* A   = ws + NN;                     // N*256 (agg1 uses first N*128, then agg2)
    float* B   = A + (size_t)NN * CH;         // N*256 (h)
    float* C   = B + (size_t)NN * CH;         // N*128 (z)
    // total ws need: N*(1+256+256+128)*4 = ~128.2 MB

    // phase 1: degrees + scatter x
    k_zero<<<2048, 256, 0, stream>>>(cnt, (NN + NN * CIN) / 4);  // cnt + agg1 contiguous
    k_count<<<(NE + 255) / 256, 256, 0, stream>>>(dst, cnt);
    k_scatter<CIN><<<(NE * (CIN / 4) + 255) / 256, 256, 0, stream>>>(src, dst, x, A);
    k_sage1<<<(NN + 31) / 32, 256, 0, stream>>>(x, A, cnt, W1l, W1r, b1,
                                                bn1g, bn1b, bn1m, bn1v, B);
    // phase 2: scatter h
    k_zero<<<2048, 256, 0, stream>>>(A, NN * CH / 4);
    k_scatter<CH><<<(NE * (CH / 4) + 255) / 256, 256, 0, stream>>>(src, dst, B, A);
    k_sage2<<<(NN + 23) / 24, 256, 0, stream>>>(B, A, cnt, W2l, W2r, b2, C);
    // phase 3: decoder
    k_mlp<<<NPE / 16, 256, 0, stream>>>(C, pu, pv,
                                        pW1, pb1, pg1, pbb1, pm1, pv1,
                                        pW2, pb2, pg2, pbb2, pm2, pv2,
                                        pW3, pb3, out);
}

// Round 2
// 742.613 us; speedup vs baseline: 9.1218x; 9.1218x over previous
//
#include <hip/hip_runtime.h>
#include <hip/hip_bf16.h>

#define NN   50000
#define NE   640000
#define NPE  500000
#define FEPS 1e-5f

typedef __attribute__((ext_vector_type(8))) short          bf16x8;
typedef __attribute__((ext_vector_type(8))) unsigned short u16x8;
typedef __attribute__((ext_vector_type(4))) float          f32x4;

__device__ inline float b2f(unsigned short u) {
    union { unsigned int i; float f; } c; c.i = (unsigned int)u << 16; return c.f;
}
__device__ inline unsigned short f2b(float f) {
    __hip_bfloat16 h = __float2bfloat16(f);
    return *reinterpret_cast<unsigned short*>(&h);
}

// ---------------- utility kernels ----------------
__global__ void k_zero_i(int4* p, int n) {
    int i = blockIdx.x * blockDim.x + threadIdx.x;
    if (i < n) p[i] = make_int4(0, 0, 0, 0);
}

__global__ void k_f2b(const float* __restrict__ in, unsigned short* __restrict__ out, int n8) {
    int i = blockIdx.x * blockDim.x + threadIdx.x;
    if (i >= n8) return;
    const float4* p = (const float4*)in + 2 * (size_t)i;
    float4 a = p[0], c = p[1];
    u16x8 o;
    o[0] = f2b(a.x); o[1] = f2b(a.y); o[2] = f2b(a.z); o[3] = f2b(a.w);
    o[4] = f2b(c.x); o[5] = f2b(c.y); o[6] = f2b(c.z); o[7] = f2b(c.w);
    *((u16x8*)out + i) = o;
}

// ---------------- CSR build ----------------
__global__ void k_hist(const int* __restrict__ dst, int* __restrict__ cnt) {
    int e = blockIdx.x * blockDim.x + threadIdx.x;
    if (e < NE) atomicAdd(&cnt[dst[e]], 1);
}

__global__ void k_scan(const int* __restrict__ cnt, int* __restrict__ rowptr) {
    __shared__ int wsum[16];
    __shared__ int base;
    int t = threadIdx.x, lane = t & 63, w = t >> 6;
    if (t == 0) base = 0;
    __syncthreads();
    for (int i0 = 0; i0 < NN; i0 += 1024) {
        int i = i0 + t;
        int v = (i < NN) ? cnt[i] : 0;
        int s = v;
#pragma unroll
        for (int d = 1; d < 64; d <<= 1) { int u = __shfl_up(s, d, 64); if (lane >= d) s += u; }
        if (lane == 63) wsum[w] = s;
        __syncthreads();
        if (w == 0) {
            int ws = (lane < 16) ? wsum[lane] : 0;
#pragma unroll
            for (int d = 1; d < 16; d <<= 1) { int u = __shfl_up(ws, d, 64); if (lane >= d) ws += u; }
            if (lane < 16) wsum[lane] = ws;
        }
        __syncthreads();
        int wbase = (w == 0) ? 0 : wsum[w - 1];
        if (i < NN) rowptr[i] = base + wbase + (s - v);
        int total = wsum[15];
        __syncthreads();
        if (t == 0) base += total;
        __syncthreads();
    }
    if (t == 0) rowptr[NN] = base;
}

__global__ void k_fill(const int* __restrict__ src, const int* __restrict__ dst,
                       const int* __restrict__ rowptr, int* __restrict__ cursor,
                       int* __restrict__ col) {
    int e = blockIdx.x * blockDim.x + threadIdx.x;
    if (e >= NE) return;
    int d = dst[e];
    int slot = atomicAdd(&cursor[d], 1);
    col[rowptr[d] + slot] = src[e];
}

// ---------------- gather-mean (CSR) ----------------
template <int C>
__global__ __launch_bounds__(256) void k_mean(const unsigned short* __restrict__ feat,
                                              const int* __restrict__ rowptr,
                                              const int* __restrict__ col,
                                              unsigned short* __restrict__ outm) {
    const int PER = C / 64;
    int node = blockIdx.x * 4 + (threadIdx.x >> 6);
    int lane = threadIdx.x & 63;
    if (node >= NN) return;
    int beg = rowptr[node], end = rowptr[node + 1];
    float acc[PER];
#pragma unroll
    for (int p2 = 0; p2 < PER; ++p2) acc[p2] = 0.f;
    for (int j = beg; j < end; ++j) {
        int s = col[j];
        const unsigned short* r = feat + (size_t)s * C + lane * PER;
        if (PER == 2) {
            unsigned int v = *(const unsigned int*)r;
            acc[0] += b2f(v & 0xffff); acc[1] += b2f(v >> 16);
        } else {
            uint2 v = *(const uint2*)r;
            acc[0] += b2f(v.x & 0xffff); acc[1] += b2f(v.x >> 16);
            acc[2] += b2f(v.y & 0xffff); acc[3] += b2f(v.y >> 16);
        }
    }
    float inv = 1.f / fmaxf((float)(end - beg), 1.f);
    unsigned short* o = outm + (size_t)node * C + lane * PER;
    if (PER == 2) {
        unsigned int v = (unsigned int)f2b(acc[0] * inv) | ((unsigned int)f2b(acc[1] * inv) << 16);
        *(unsigned int*)o = v;
    } else {
        uint2 v;
        v.x = (unsigned int)f2b(acc[0] * inv) | ((unsigned int)f2b(acc[1] * inv) << 16);
        v.y = (unsigned int)f2b(acc[2] * inv) | ((unsigned int)f2b(acc[3] * inv) << 16);
        *(uint2*)o = v;
    }
}

// ---------------- SAGE layer 1 (MFMA): h = relu(bn(mean@Wl^T + x@Wr^T + b)) ----------------
__global__ __launch_bounds__(256) void k_sage1(
    const unsigned short* __restrict__ mean, const unsigned short* __restrict__ self,
    const unsigned short* __restrict__ Wl, const unsigned short* __restrict__ Wr,  // [256][128]
    const float* __restrict__ b, const float* __restrict__ bg, const float* __restrict__ bb,
    const float* __restrict__ bm, const float* __restrict__ bv,
    unsigned short* __restrict__ hout) {  // [NN][256]
    __shared__ unsigned short ms[64 * 128];
    __shared__ unsigned short xs[64 * 128];
    int t = threadIdx.x;
    int n0 = blockIdx.x * 64;
    for (int j = 0; j < 4; ++j) {
        int idx = t + j * 256;
        int row = idx >> 4, c16 = idx & 15;
        int node = n0 + row;
        u16x8 v = {0,0,0,0,0,0,0,0}, v2 = {0,0,0,0,0,0,0,0};
        if (node < NN) {
            v  = *(const u16x8*)(mean + (size_t)node * 128 + c16 * 8);
            v2 = *(const u16x8*)(self + (size_t)node * 128 + c16 * 8);
        }
        int byte = row * 256 + ((c16 * 16) ^ ((row & 7) << 4));
        *(u16x8*)((char*)ms + byte) = v;
        *(u16x8*)((char*)xs + byte) = v2;
    }
    __syncthreads();
    int w = t >> 6, l = t & 63, lr = l & 15, lh = l >> 4;
    f32x4 acc[4][4];
#pragma unroll
    for (int mi = 0; mi < 4; ++mi)
#pragma unroll
        for (int ni = 0; ni < 4; ++ni) { acc[mi][ni][0]=0; acc[mi][ni][1]=0; acc[mi][ni][2]=0; acc[mi][ni][3]=0; }
#pragma unroll
    for (int half = 0; half < 2; ++half) {
        const unsigned short* A = half ? xs : ms;
        const unsigned short* W = half ? Wr : Wl;
#pragma unroll
        for (int ks = 0; ks < 4; ++ks) {
            int k0 = ks * 32;
            bf16x8 a[4], wf[4];
#pragma unroll
            for (int mi = 0; mi < 4; ++mi) {
                int row = mi * 16 + lr;
                int byte = row * 256 + ((k0 * 2 + lh * 16) ^ ((row & 7) << 4));
                a[mi] = *(const bf16x8*)((const char*)A + byte);
            }
#pragma unroll
            for (int ni = 0; ni < 4; ++ni) {
                int wrow = w * 64 + ni * 16 + lr;
                wf[ni] = *(const bf16x8*)(W + (size_t)wrow * 128 + k0 + lh * 8);
            }
#pragma unroll
            for (int mi = 0; mi < 4; ++mi)
#pragma unroll
                for (int ni = 0; ni < 4; ++ni)
                    acc[mi][ni] = __builtin_amdgcn_mfma_f32_16x16x32_bf16(a[mi], wf[ni], acc[mi][ni], 0, 0, 0);
        }
    }
#pragma unroll
    for (int ni = 0; ni < 4; ++ni) {
        int ch = w * 64 + ni * 16 + lr;
        float sc = bg[ch] * rsqrtf(bv[ch] + FEPS);
        float sh = bb[ch] - bm[ch] * sc;
        float bias = b[ch];
#pragma unroll
        for (int mi = 0; mi < 4; ++mi)
#pragma unroll
            for (int r = 0; r < 4; ++r) {
                int node = n0 + mi * 16 + lh * 4 + r;
                if (node < NN) {
                    float vv = (acc[mi][ni][r] + bias) * sc + sh;
                    hout[(size_t)node * 256 + ch] = f2b(fmaxf(vv, 0.f));
                }
            }
    }
}

// ---------------- SAGE layer 2 (MFMA): z = mean2@Wl^T + h@Wr^T + b ----------------
__global__ __launch_bounds__(256) void k_sage2(
    const unsigned short* __restrict__ mean, const unsigned short* __restrict__ self,
    const unsigned short* __restrict__ Wl, const unsigned short* __restrict__ Wr,  // [128][256]
    const float* __restrict__ b,
    unsigned short* __restrict__ zout) {  // [NN][128]
    __shared__ unsigned short ms[64 * 256];
    __shared__ unsigned short hs[64 * 256];
    int t = threadIdx.x;
    int n0 = blockIdx.x * 64;
    for (int j = 0; j < 8; ++j) {
        int idx = t + j * 256;
        int row = idx >> 5, c16 = idx & 31;
        int node = n0 + row;
        u16x8 v = {0,0,0,0,0,0,0,0}, v2 = {0,0,0,0,0,0,0,0};
        if (node < NN) {
            v  = *(const u16x8*)(mean + (size_t)node * 256 + c16 * 8);
            v2 = *(const u16x8*)(self + (size_t)node * 256 + c16 * 8);
        }
        int byte = row * 512 + ((c16 * 16) ^ ((row & 7) << 4));
        *(u16x8*)((char*)ms + byte) = v;
        *(u16x8*)((char*)hs + byte) = v2;
    }
    __syncthreads();
    int w = t >> 6, l = t & 63, lr = l & 15, lh = l >> 4;
    f32x4 acc[4][2];
#pragma unroll
    for (int mi = 0; mi < 4; ++mi)
#pragma unroll
        for (int ni = 0; ni < 2; ++ni) { acc[mi][ni][0]=0; acc[mi][ni][1]=0; acc[mi][ni][2]=0; acc[mi][ni][3]=0; }
#pragma unroll
    for (int half = 0; half < 2; ++half) {
        const unsigned short* A = half ? hs : ms;
        const unsigned short* W = half ? Wr : Wl;
#pragma unroll
        for (int ks = 0; ks < 8; ++ks) {
            int k0 = ks * 32;
            bf16x8 a[4], wf[2];
#pragma unroll
            for (int mi = 0; mi < 4; ++mi) {
                int row = mi * 16 + lr;
                int byte = row * 512 + ((k0 * 2 + lh * 16) ^ ((row & 7) << 4));
                a[mi] = *(const bf16x8*)((const char*)A + byte);
            }
#pragma unroll
            for (int ni = 0; ni < 2; ++ni) {
                int wrow = w * 32 + ni * 16 + lr;
                wf[ni] = *(const bf16x8*)(W + (size_t)wrow * 256 + k0 + lh * 8);
            }
#pragma unroll
            for (int mi = 0; mi < 4; ++mi)
#pragma unroll
                for (int ni = 0; ni < 2; ++ni)
                    acc[mi][ni] = __builtin_amdgcn_mfma_f32_16x16x32_bf16(a[mi], wf[ni], acc[mi][ni], 0, 0, 0);
        }
    }
#pragma unroll
    for (int ni = 0; ni < 2; ++ni) {
        int ch = w * 32 + ni * 16 + lr;
        float bias = b[ch];
#pragma unroll
        for (int mi = 0; mi < 4; ++mi)
#pragma unroll
            for (int r = 0; r < 4; ++r) {
                int node = n0 + mi * 16 + lh * 4 + r;
                if (node < NN)
                    zout[(size_t)node * 128 + ch] = f2b(acc[mi][ni][r] + bias);
            }
    }
}

// ---------------- fused link-predictor MLP (MFMA), 64 edges / block ----------------
__global__ __launch_bounds__(256) void k_mlp(
    const unsigned short* __restrict__ z, const int* __restrict__ pu, const int* __restrict__ pv,
    const unsigned short* __restrict__ W1, const float* __restrict__ b1,
    const float* __restrict__ g1, const float* __restrict__ be1,
    const float* __restrict__ m1, const float* __restrict__ v1,
    const unsigned short* __restrict__ W2, const float* __restrict__ b2,
    const float* __restrict__ g2, const float* __restrict__ be2,
    const float* __restrict__ m2, const float* __restrict__ v2,
    const float* __restrict__ W3, const float* __restrict__ b3,
    float* __restrict__ out) {
    __shared__ unsigned short q[64 * 256];   // L1 input (512B rows, swizzled); later reused for q2 (256B rows)
    __shared__ unsigned short q1[64 * 256];  // L1 output / L2 input
    int t = threadIdx.x;
    int e0 = blockIdx.x * 64;
    for (int j = 0; j < 8; ++j) {
        int idx = t + j * 256;
        int edge = idx >> 5, half = (idx >> 4) & 1, c16 = idx & 15;
        int ge = e0 + edge;
        int node = 0;
        if (ge < NPE) node = half ? pv[ge] : pu[ge];
        u16x8 v = *(const u16x8*)(z + (size_t)node * 128 + c16 * 8);
        int byte = edge * 512 + ((half * 256 + c16 * 16) ^ ((edge & 7) << 4));
        *(u16x8*)((char*)q + byte) = v;
    }
    __syncthreads();
    int w = t >> 6, l = t & 63, lr = l & 15, lh = l >> 4;
    {   // layer 1: [64x256] @ W1^T(256x256)
        f32x4 acc[4][4];
#pragma unroll
        for (int mi = 0; mi < 4; ++mi)
#pragma unroll
            for (int ni = 0; ni < 4; ++ni) { acc[mi][ni][0]=0; acc[mi][ni][1]=0; acc[mi][ni][2]=0; acc[mi][ni][3]=0; }
#pragma unroll
        for (int ks = 0; ks < 8; ++ks) {
            int k0 = ks * 32;
            bf16x8 a[4], wf[4];
#pragma unroll
            for (int mi = 0; mi < 4; ++mi) {
                int row = mi * 16 + lr;
                int byte = row * 512 + ((k0 * 2 + lh * 16) ^ ((row & 7) << 4));
                a[mi] = *(const bf16x8*)((const char*)q + byte);
            }
#pragma unroll
            for (int ni = 0; ni < 4; ++ni) {
                int wrow = w * 64 + ni * 16 + lr;
                wf[ni] = *(const bf16x8*)(W1 + (size_t)wrow * 256 + k0 + lh * 8);
            }
#pragma unroll
            for (int mi = 0; mi < 4; ++mi)
#pragma unroll
                for (int ni = 0; ni < 4; ++ni)
                    acc[mi][ni] = __builtin_amdgcn_mfma_f32_16x16x32_bf16(a[mi], wf[ni], acc[mi][ni], 0, 0, 0);
        }
#pragma unroll
        for (int ni = 0; ni < 4; ++ni) {
            int ch = w * 64 + ni * 16 + lr;
            float sc = g1[ch] * rsqrtf(v1[ch] + FEPS);
            float sh = be1[ch] - m1[ch] * sc;
            float bias = b1[ch];
#pragma unroll
            for (int mi = 0; mi < 4; ++mi)
#pragma unroll
                for (int r = 0; r < 4; ++r) {
                    int row = mi * 16 + lh * 4 + r;
                    float vv = fmaxf((acc[mi][ni][r] + bias) * sc + sh, 0.f);
                    int byte = row * 512 + ((ch * 2) ^ ((row & 7) << 4));
                    *(unsigned short*)((char*)q1 + byte) = f2b(vv);
                }
        }
    }
    __syncthreads();
    {   // layer 2: [64x256] @ W2^T(128x256) -> q2 (stored in q region, 256B rows)
        f32x4 acc[4][2];
#pragma unroll
        for (int mi = 0; mi < 4; ++mi)
#pragma unroll
            for (int ni = 0; ni < 2; ++ni) { acc[mi][ni][0]=0; acc[mi][ni][1]=0; acc[mi][ni][2]=0; acc[mi][ni][3]=0; }
#pragma unroll
        for (int ks = 0; ks < 8; ++ks) {
            int k0 = ks * 32;
            bf16x8 a[4], wf[2];
#pragma unroll
            for (int mi = 0; mi < 4; ++mi) {
                int row = mi * 16 + lr;
                int byte = row * 512 + ((k0 * 2 + lh * 16) ^ ((row & 7) << 4));
                a[mi] = *(const bf16x8*)((const char*)q1 + byte);
            }
#pragma unroll
            for (int ni = 0; ni < 2; ++ni) {
                int wrow = w * 32 + ni * 16 + lr;
                wf[ni] = *(const bf16x8*)(W2 + (size_t)wrow * 256 + k0 + lh * 8);
            }
#pragma unroll
            for (int mi = 0; mi < 4; ++mi)
#pragma unroll
                for (int ni = 0; ni < 2; ++ni)
                    acc[mi][ni] = __builtin_amdgcn_mfma_f32_16x16x32_bf16(a[mi], wf[ni], acc[mi][ni], 0, 0, 0);
        }
#pragma unroll
        for (int ni = 0; ni < 2; ++ni) {
            int ch = w * 32 + ni * 16 + lr;
            float sc = g2[ch] * rsqrtf(v2[ch] + FEPS);
            float sh = be2[ch] - m2[ch] * sc;
            float bias = b2[ch];
#pragma unroll
            for (int mi = 0; mi < 4; ++mi)
#pragma unroll
                for (int r = 0; r < 4; ++r) {
                    int row = mi * 16 + lh * 4 + r;
                    float vv = fmaxf((acc[mi][ni][r] + bias) * sc + sh, 0.f);
                    int byte = row * 256 + ((ch * 2) ^ ((row & 7) << 4));
                    *(unsigned short*)((char*)q + byte) = f2b(vv);
                }
        }
    }
    __syncthreads();
    {   // layer 3: [64x128] @ W3(128) -> out; 4 threads per edge
        int edge = t >> 2, part = t & 3;
        float p = 0.f;
#pragma unroll
        for (int s = 0; s < 4; ++s) {
            int byte = edge * 256 + (((part * 64 + s * 16)) ^ ((edge & 7) << 4));
            u16x8 v = *(const u16x8*)((const char*)q + byte);
#pragma unroll
            for (int jj = 0; jj < 8; ++jj)
                p += b2f((unsigned short)v[jj]) * W3[part * 32 + s * 8 + jj];
        }
        p += __shfl_xor(p, 1, 64);
        p += __shfl_xor(p, 2, 64);
        int ge = e0 + edge;
        if (part == 0 && ge < NPE) out[ge] = p + b3[0];
    }
}

extern "C" void kernel_launch(void* const* d_in, const int* in_sizes, int n_in,
                              void* d_out, int out_size, void* d_ws, size_t ws_size,
                              hipStream_t stream) {
    const float* x    = (const float*)d_in[0];
    const int*   ei   = (const int*)d_in[1];
    const int*   pei  = (const int*)d_in[2];
    const float* W1l  = (const float*)d_in[3];
    const float* W1r  = (const float*)d_in[4];
    const float* b1   = (const float*)d_in[5];
    const float* bn1g = (const float*)d_in[6];
    const float* bn1b = (const float*)d_in[7];
    const float* bn1m = (const float*)d_in[8];
    const float* bn1v = (const float*)d_in[9];
    const float* W2l  = (const float*)d_in[10];
    const float* W2r  = (const float*)d_in[11];
    const float* b2   = (const float*)d_in[12];
    const float* pW1  = (const float*)d_in[13];
    const float* pb1  = (const float*)d_in[14];
    const float* pg1  = (const float*)d_in[15];
    const float* pbb1 = (const float*)d_in[16];
    const float* pm1  = (const float*)d_in[17];
    const float* pv1  = (const float*)d_in[18];
    const float* pW2  = (const float*)d_in[19];
    const float* pb2  = (const float*)d_in[20];
    const float* pg2  = (const float*)d_in[21];
    const float* pbb2 = (const float*)d_in[22];
    const float* pm2  = (const float*)d_in[23];
    const float* pv2  = (const float*)d_in[24];
    const float* pW3  = (const float*)d_in[25];
    const float* pb3  = (const float*)d_in[26];
    float* out = (float*)d_out;

    const int* src = ei;
    const int* dst = ei + NE;
    const int* pu  = pei;
    const int* pv  = pei + NPE;

    char* p = (char*)d_ws;
    auto alloc = [&](size_t bytes) -> char* {
        char* r = p; p += (bytes + 255) & ~(size_t)255; return r;
    };
    int* cnt    = (int*)alloc((size_t)NN * 4);
    int* cursor = (int*)alloc((size_t)NN * 4);
    int* rowptr = (int*)alloc((size_t)(NN + 1) * 4);
    int* col    = (int*)alloc((size_t)NE * 4);
    unsigned short* xbf  = (unsigned short*)alloc((size_t)NN * 128 * 2);
    unsigned short* mx   = (unsigned short*)alloc((size_t)NN * 128 * 2);
    unsigned short* hbf  = (unsigned short*)alloc((size_t)NN * 256 * 2);
    unsigned short* m2b  = (unsigned short*)alloc((size_t)NN * 256 * 2);
    unsigned short* zbf  = (unsigned short*)alloc((size_t)NN * 128 * 2);
    unsigned short* W1lb = (unsigned short*)alloc((size_t)256 * 128 * 2);
    unsigned short* W1rb = (unsigned short*)alloc((size_t)256 * 128 * 2);
    unsigned short* W2lb = (unsigned short*)alloc((size_t)128 * 256 * 2);
    unsigned short* W2rb = (unsigned short*)alloc((size_t)128 * 256 * 2);
    unsigned short* pW1b = (unsigned short*)alloc((size_t)256 * 256 * 2);
    unsigned short* pW2b = (unsigned short*)alloc((size_t)128 * 256 * 2);

    // zero cnt + cursor (contiguous, padded to 256B each): 2*200704 bytes = 25088 int4
    k_zero_i<<<98, 256, 0, stream>>>((int4*)cnt, 25088);

    // bf16 conversions
    k_f2b<<<3125, 256, 0, stream>>>(x,   xbf,  NN * 128 / 8);
    k_f2b<<<16,   256, 0, stream>>>(W1l, W1lb, 256 * 128 / 8);
    k_f2b<<<16,   256, 0, stream>>>(W1r, W1rb, 256 * 128 / 8);
    k_f2b<<<16,   256, 0, stream>>>(W2l, W2lb, 128 * 256 / 8);
    k_f2b<<<16,   256, 0, stream>>>(W2r, W2rb, 128 * 256 / 8);
    k_f2b<<<32,   256, 0, stream>>>(pW1, pW1b, 256 * 256 / 8);
    k_f2b<<<16,   256, 0, stream>>>(pW2, pW2b, 128 * 256 / 8);

    // CSR build
    k_hist<<<2500, 256, 0, stream>>>(dst, cnt);
    k_scan<<<1, 1024, 0, stream>>>(cnt, rowptr);
    k_fill<<<2500, 256, 0, stream>>>(src, dst, rowptr, cursor, col);

    // encoder
    k_mean<128><<<12500, 256, 0, stream>>>(xbf, rowptr, col, mx);
    k_sage1<<<782, 256, 0, stream>>>(mx, xbf, W1lb, W1rb, b1, bn1g, bn1b, bn1m, bn1v, hbf);
    k_mean<256><<<12500, 256, 0, stream>>>(hbf, rowptr, col, m2b);
    k_sage2<<<782, 256, 0, stream>>>(m2b, hbf, W2lb, W2rb, b2, zbf);

    // decoder
    k_mlp<<<(NPE + 63) / 64, 256, 0, stream>>>(zbf, pu, pv,
                                               pW1b, pb1, pg1, pbb1, pm1, pv1,
                                               pW2b, pb2, pg2, pbb2, pm2, pv2,
                                               pW3, pb3, out);
}

// Round 3
// 451.684 us; speedup vs baseline: 14.9971x; 1.6441x over previous
//
#include <hip/hip_runtime.h>
#include <hip/hip_bf16.h>

#define NN   50000
#define NE   640000
#define NPE  500000
#define FEPS 1e-5f

typedef __attribute__((ext_vector_type(8))) short          bf16x8;
typedef __attribute__((ext_vector_type(8))) unsigned short u16x8;
typedef __attribute__((ext_vector_type(4))) float          f32x4;

__device__ inline float b2f(unsigned short u) {
    union { unsigned int i; float f; } c; c.i = (unsigned int)u << 16; return c.f;
}
__device__ inline unsigned short f2b(float f) {
    __hip_bfloat16 h = __float2bfloat16(f);
    return *reinterpret_cast<unsigned short*>(&h);
}

// ---------------- utility kernels ----------------
__global__ void k_zero_i(int4* p, int n) {
    int i = blockIdx.x * blockDim.x + threadIdx.x;
    if (i < n) p[i] = make_int4(0, 0, 0, 0);
}

__global__ void k_f2b(const float* __restrict__ in, unsigned short* __restrict__ out, int n8) {
    int i = blockIdx.x * blockDim.x + threadIdx.x;
    if (i >= n8) return;
    const float4* p = (const float4*)in + 2 * (size_t)i;
    float4 a = p[0], c = p[1];
    u16x8 o;
    o[0] = f2b(a.x); o[1] = f2b(a.y); o[2] = f2b(a.z); o[3] = f2b(a.w);
    o[4] = f2b(c.x); o[5] = f2b(c.y); o[6] = f2b(c.z); o[7] = f2b(c.w);
    *((u16x8*)out + i) = o;
}

// ---------------- CSR build ----------------
__global__ void k_hist(const int* __restrict__ dst, int* __restrict__ cnt) {
    int e = blockIdx.x * blockDim.x + threadIdx.x;
    if (e < NE) atomicAdd(&cnt[dst[e]], 1);
}

__global__ void k_scan(const int* __restrict__ cnt, int* __restrict__ rowptr) {
    __shared__ int wsum[16];
    __shared__ int base;
    int t = threadIdx.x, lane = t & 63, w = t >> 6;
    if (t == 0) base = 0;
    __syncthreads();
    for (int i0 = 0; i0 < NN; i0 += 1024) {
        int i = i0 + t;
        int v = (i < NN) ? cnt[i] : 0;
        int s = v;
#pragma unroll
        for (int d = 1; d < 64; d <<= 1) { int u = __shfl_up(s, d, 64); if (lane >= d) s += u; }
        if (lane == 63) wsum[w] = s;
        __syncthreads();
        if (w == 0) {
            int ws = (lane < 16) ? wsum[lane] : 0;
#pragma unroll
            for (int d = 1; d < 16; d <<= 1) { int u = __shfl_up(ws, d, 64); if (lane >= d) ws += u; }
            if (lane < 16) wsum[lane] = ws;
        }
        __syncthreads();
        int wbase = (w == 0) ? 0 : wsum[w - 1];
        if (i < NN) rowptr[i] = base + wbase + (s - v);
        int total = wsum[15];
        __syncthreads();
        if (t == 0) base += total;
        __syncthreads();
    }
    if (t == 0) rowptr[NN] = base;
}

__global__ void k_fill(const int* __restrict__ src, const int* __restrict__ dst,
                       const int* __restrict__ rowptr, int* __restrict__ cursor,
                       int* __restrict__ col) {
    int e = blockIdx.x * blockDim.x + threadIdx.x;
    if (e >= NE) return;
    int d = dst[e];
    int slot = atomicAdd(&cursor[d], 1);
    col[rowptr[d] + slot] = src[e];
}

// ---------------- gather-mean (CSR), 4-deep unrolled ----------------
template <int C>
__global__ __launch_bounds__(256) void k_mean(const unsigned short* __restrict__ feat,
                                              const int* __restrict__ rowptr,
                                              const int* __restrict__ col,
                                              unsigned short* __restrict__ outm) {
    const int PER = C / 64;
    int node = blockIdx.x * 4 + (threadIdx.x >> 6);
    int lane = threadIdx.x & 63;
    if (node >= NN) return;
    int beg = rowptr[node], end = rowptr[node + 1];
    float acc[PER];
#pragma unroll
    for (int p2 = 0; p2 < PER; ++p2) acc[p2] = 0.f;
    int j = beg;
    for (; j + 4 <= end; j += 4) {
        int s0 = col[j], s1 = col[j + 1], s2 = col[j + 2], s3 = col[j + 3];
        if (PER == 2) {
            unsigned int v0 = *(const unsigned int*)(feat + (size_t)s0 * C + lane * 2);
            unsigned int v1 = *(const unsigned int*)(feat + (size_t)s1 * C + lane * 2);
            unsigned int v2 = *(const unsigned int*)(feat + (size_t)s2 * C + lane * 2);
            unsigned int v3 = *(const unsigned int*)(feat + (size_t)s3 * C + lane * 2);
            acc[0] += b2f(v0 & 0xffff) + b2f(v1 & 0xffff) + b2f(v2 & 0xffff) + b2f(v3 & 0xffff);
            acc[1] += b2f(v0 >> 16)    + b2f(v1 >> 16)    + b2f(v2 >> 16)    + b2f(v3 >> 16);
        } else {
            uint2 v0 = *(const uint2*)(feat + (size_t)s0 * C + lane * 4);
            uint2 v1 = *(const uint2*)(feat + (size_t)s1 * C + lane * 4);
            uint2 v2 = *(const uint2*)(feat + (size_t)s2 * C + lane * 4);
            uint2 v3 = *(const uint2*)(feat + (size_t)s3 * C + lane * 4);
            acc[0] += b2f(v0.x & 0xffff) + b2f(v1.x & 0xffff) + b2f(v2.x & 0xffff) + b2f(v3.x & 0xffff);
            acc[1] += b2f(v0.x >> 16)    + b2f(v1.x >> 16)    + b2f(v2.x >> 16)    + b2f(v3.x >> 16);
            acc[2] += b2f(v0.y & 0xffff) + b2f(v1.y & 0xffff) + b2f(v2.y & 0xffff) + b2f(v3.y & 0xffff);
            acc[3] += b2f(v0.y >> 16)    + b2f(v1.y >> 16)    + b2f(v2.y >> 16)    + b2f(v3.y >> 16);
        }
    }
    for (; j < end; ++j) {
        int s = col[j];
        if (PER == 2) {
            unsigned int v = *(const unsigned int*)(feat + (size_t)s * C + lane * 2);
            acc[0] += b2f(v & 0xffff); acc[1] += b2f(v >> 16);
        } else {
            uint2 v = *(const uint2*)(feat + (size_t)s * C + lane * 4);
            acc[0] += b2f(v.x & 0xffff); acc[1] += b2f(v.x >> 16);
            acc[2] += b2f(v.y & 0xffff); acc[3] += b2f(v.y >> 16);
        }
    }
    float inv = 1.f / fmaxf((float)(end - beg), 1.f);
    unsigned short* o = outm + (size_t)node * C + lane * PER;
    if (PER == 2) {
        unsigned int v = (unsigned int)f2b(acc[0] * inv) | ((unsigned int)f2b(acc[1] * inv) << 16);
        *(unsigned int*)o = v;
    } else {
        uint2 v;
        v.x = (unsigned int)f2b(acc[0] * inv) | ((unsigned int)f2b(acc[1] * inv) << 16);
        v.y = (unsigned int)f2b(acc[2] * inv) | ((unsigned int)f2b(acc[3] * inv) << 16);
        *(uint2*)o = v;
    }
}

// ---------------- SAGE layer 1 (MFMA): h = relu(bn(mean@Wl^T + x@Wr^T + b)) ----------------
__global__ __launch_bounds__(256) void k_sage1(
    const unsigned short* __restrict__ mean, const unsigned short* __restrict__ self,
    const unsigned short* __restrict__ Wl, const unsigned short* __restrict__ Wr,  // [256][128]
    const float* __restrict__ b, const float* __restrict__ bg, const float* __restrict__ bb,
    const float* __restrict__ bm, const float* __restrict__ bv,
    unsigned short* __restrict__ hout) {  // [NN][256]
    __shared__ unsigned short ms[64 * 128];
    __shared__ unsigned short xs[64 * 128];
    int t = threadIdx.x;
    int n0 = blockIdx.x * 64;
    for (int j = 0; j < 4; ++j) {
        int idx = t + j * 256;
        int row = idx >> 4, c16 = idx & 15;
        int node = n0 + row;
        u16x8 v = {0,0,0,0,0,0,0,0}, v2 = {0,0,0,0,0,0,0,0};
        if (node < NN) {
            v  = *(const u16x8*)(mean + (size_t)node * 128 + c16 * 8);
            v2 = *(const u16x8*)(self + (size_t)node * 128 + c16 * 8);
        }
        int byte = row * 256 + ((c16 * 16) ^ ((row & 7) << 4));
        *(u16x8*)((char*)ms + byte) = v;
        *(u16x8*)((char*)xs + byte) = v2;
    }
    __syncthreads();
    int w = t >> 6, l = t & 63, lr = l & 15, lh = l >> 4;
    f32x4 acc[4][4];
#pragma unroll
    for (int mi = 0; mi < 4; ++mi)
#pragma unroll
        for (int ni = 0; ni < 4; ++ni) { acc[mi][ni][0]=0; acc[mi][ni][1]=0; acc[mi][ni][2]=0; acc[mi][ni][3]=0; }
#pragma unroll
    for (int half = 0; half < 2; ++half) {
        const unsigned short* A = half ? xs : ms;
        const unsigned short* W = half ? Wr : Wl;
#pragma unroll
        for (int ks = 0; ks < 4; ++ks) {
            int k0 = ks * 32;
            bf16x8 a[4], wf[4];
#pragma unroll
            for (int mi = 0; mi < 4; ++mi) {
                int row = mi * 16 + lr;
                int byte = row * 256 + ((k0 * 2 + lh * 16) ^ ((row & 7) << 4));
                a[mi] = *(const bf16x8*)((const char*)A + byte);
            }
#pragma unroll
            for (int ni = 0; ni < 4; ++ni) {
                int wrow = w * 64 + ni * 16 + lr;
                wf[ni] = *(const bf16x8*)(W + (size_t)wrow * 128 + k0 + lh * 8);
            }
#pragma unroll
            for (int mi = 0; mi < 4; ++mi)
#pragma unroll
                for (int ni = 0; ni < 4; ++ni)
                    acc[mi][ni] = __builtin_amdgcn_mfma_f32_16x16x32_bf16(a[mi], wf[ni], acc[mi][ni], 0, 0, 0);
        }
    }
#pragma unroll
    for (int ni = 0; ni < 4; ++ni) {
        int ch = w * 64 + ni * 16 + lr;
        float sc = bg[ch] * rsqrtf(bv[ch] + FEPS);
        float sh = bb[ch] - bm[ch] * sc;
        float bias = b[ch];
#pragma unroll
        for (int mi = 0; mi < 4; ++mi)
#pragma unroll
            for (int r = 0; r < 4; ++r) {
                int node = n0 + mi * 16 + lh * 4 + r;
                if (node < NN) {
                    float vv = (acc[mi][ni][r] + bias) * sc + sh;
                    hout[(size_t)node * 256 + ch] = f2b(fmaxf(vv, 0.f));
                }
            }
    }
}

// ---------------- SAGE layer 2 (MFMA): z = mean2@Wl^T + h@Wr^T + b ----------------
__global__ __launch_bounds__(256) void k_sage2(
    const unsigned short* __restrict__ mean, const unsigned short* __restrict__ self,
    const unsigned short* __restrict__ Wl, const unsigned short* __restrict__ Wr,  // [128][256]
    const float* __restrict__ b,
    unsigned short* __restrict__ zout) {  // [NN][128]
    __shared__ unsigned short ms[64 * 256];
    __shared__ unsigned short hs[64 * 256];
    int t = threadIdx.x;
    int n0 = blockIdx.x * 64;
    for (int j = 0; j < 8; ++j) {
        int idx = t + j * 256;
        int row = idx >> 5, c16 = idx & 31;
        int node = n0 + row;
        u16x8 v = {0,0,0,0,0,0,0,0}, v2 = {0,0,0,0,0,0,0,0};
        if (node < NN) {
            v  = *(const u16x8*)(mean + (size_t)node * 256 + c16 * 8);
            v2 = *(const u16x8*)(self + (size_t)node * 256 + c16 * 8);
        }
        int byte = row * 512 + ((c16 * 16) ^ ((row & 7) << 4));
        *(u16x8*)((char*)ms + byte) = v;
        *(u16x8*)((char*)hs + byte) = v2;
    }
    __syncthreads();
    int w = t >> 6, l = t & 63, lr = l & 15, lh = l >> 4;
    f32x4 acc[4][2];
#pragma unroll
    for (int mi = 0; mi < 4; ++mi)
#pragma unroll
        for (int ni = 0; ni < 2; ++ni) { acc[mi][ni][0]=0; acc[mi][ni][1]=0; acc[mi][ni][2]=0; acc[mi][ni][3]=0; }
#pragma unroll
    for (int half = 0; half < 2; ++half) {
        const unsigned short* A = half ? hs : ms;
        const unsigned short* W = half ? Wr : Wl;
#pragma unroll
        for (int ks = 0; ks < 8; ++ks) {
            int k0 = ks * 32;
            bf16x8 a[4], wf[2];
#pragma unroll
            for (int mi = 0; mi < 4; ++mi) {
                int row = mi * 16 + lr;
                int byte = row * 512 + ((k0 * 2 + lh * 16) ^ ((row & 7) << 4));
                a[mi] = *(const bf16x8*)((const char*)A + byte);
            }
#pragma unroll
            for (int ni = 0; ni < 2; ++ni) {
                int wrow = w * 32 + ni * 16 + lr;
                wf[ni] = *(const bf16x8*)(W + (size_t)wrow * 256 + k0 + lh * 8);
            }
#pragma unroll
            for (int mi = 0; mi < 4; ++mi)
#pragma unroll
                for (int ni = 0; ni < 2; ++ni)
                    acc[mi][ni] = __builtin_amdgcn_mfma_f32_16x16x32_bf16(a[mi], wf[ni], acc[mi][ni], 0, 0, 0);
        }
    }
#pragma unroll
    for (int ni = 0; ni < 2; ++ni) {
        int ch = w * 32 + ni * 16 + lr;
        float bias = b[ch];
#pragma unroll
        for (int mi = 0; mi < 4; ++mi)
#pragma unroll
            for (int r = 0; r < 4; ++r) {
                int node = n0 + mi * 16 + lh * 4 + r;
                if (node < NN)
                    zout[(size_t)node * 128 + ch] = f2b(acc[mi][ni][r] + bias);
            }
    }
}

// ---------------- decoder precompute: Pa = (z@W1a^T)*sc1 + c1 ; Pb = (z@W1b^T)*sc1 ----------------
__global__ __launch_bounds__(256) void k_prep(
    const unsigned short* __restrict__ z,      // [NN][128]
    const unsigned short* __restrict__ W1,     // [256][256] bf16
    const float* __restrict__ b1, const float* __restrict__ g1,
    const float* __restrict__ be1, const float* __restrict__ m1, const float* __restrict__ v1,
    unsigned short* __restrict__ Pa, unsigned short* __restrict__ Pb) {
    __shared__ unsigned short zs[64 * 128];
    int t = threadIdx.x;
    int tile = blockIdx.x >> 1, side = blockIdx.x & 1;
    int n0 = tile * 64;
    for (int j = 0; j < 4; ++j) {
        int idx = t + j * 256;
        int row = idx >> 4, c16 = idx & 15;
        int node = n0 + row;
        u16x8 v = {0,0,0,0,0,0,0,0};
        if (node < NN) v = *(const u16x8*)(z + (size_t)node * 128 + c16 * 8);
        int byte = row * 256 + ((c16 * 16) ^ ((row & 7) << 4));
        *(u16x8*)((char*)zs + byte) = v;
    }
    __syncthreads();
    int w = t >> 6, l = t & 63, lr = l & 15, lh = l >> 4;
    f32x4 acc[4][4];
#pragma unroll
    for (int mi = 0; mi < 4; ++mi)
#pragma unroll
        for (int ni = 0; ni < 4; ++ni) { acc[mi][ni][0]=0; acc[mi][ni][1]=0; acc[mi][ni][2]=0; acc[mi][ni][3]=0; }
#pragma unroll
    for (int ks = 0; ks < 4; ++ks) {
        int k0 = ks * 32;
        bf16x8 a[4], wf[4];
#pragma unroll
        for (int mi = 0; mi < 4; ++mi) {
            int row = mi * 16 + lr;
            int byte = row * 256 + ((k0 * 2 + lh * 16) ^ ((row & 7) << 4));
            a[mi] = *(const bf16x8*)((const char*)zs + byte);
        }
#pragma unroll
        for (int ni = 0; ni < 4; ++ni) {
            int ch = w * 64 + ni * 16 + lr;
            wf[ni] = *(const bf16x8*)(W1 + (size_t)ch * 256 + side * 128 + k0 + lh * 8);
        }
#pragma unroll
        for (int mi = 0; mi < 4; ++mi)
#pragma unroll
            for (int ni = 0; ni < 4; ++ni)
                acc[mi][ni] = __builtin_amdgcn_mfma_f32_16x16x32_bf16(a[mi], wf[ni], acc[mi][ni], 0, 0, 0);
    }
    unsigned short* P = side ? Pb : Pa;
#pragma unroll
    for (int ni = 0; ni < 4; ++ni) {
        int ch = w * 64 + ni * 16 + lr;
        float sc = g1[ch] * rsqrtf(v1[ch] + FEPS);
        float add = side ? 0.f : ((b1[ch] - m1[ch]) * sc + be1[ch]);
#pragma unroll
        for (int mi = 0; mi < 4; ++mi)
#pragma unroll
            for (int r = 0; r < 4; ++r) {
                int node = n0 + mi * 16 + lh * 4 + r;
                if (node < NN)
                    P[(size_t)node * 256 + ch] = f2b(acc[mi][ni][r] * sc + add);
            }
    }
}

// ---------------- fused decoder: q1=relu(Pa[u]+Pb[v]); L2 GEMM; L3 dot. 64 edges/block ----------------
__global__ __launch_bounds__(256, 5) void k_mlp(
    const unsigned short* __restrict__ Pa, const unsigned short* __restrict__ Pb,
    const int* __restrict__ pu, const int* __restrict__ pv,
    const unsigned short* __restrict__ W2, const float* __restrict__ b2,
    const float* __restrict__ g2, const float* __restrict__ be2,
    const float* __restrict__ m2, const float* __restrict__ v2,
    const float* __restrict__ W3, const float* __restrict__ b3,
    float* __restrict__ out) {
    __shared__ unsigned short q1[64 * 256];   // 32 KB, single buffer (reused for q2)
    int t = threadIdx.x;
    int e0 = blockIdx.x * 64;
    for (int j = 0; j < 8; ++j) {
        int idx = t + j * 256;
        int edge = idx >> 5, c16 = idx & 31;
        int ge = e0 + edge;
        u16x8 o = {0,0,0,0,0,0,0,0};
        if (ge < NPE) {
            int u = pu[ge], vv = pv[ge];
            u16x8 A = *(const u16x8*)(Pa + (size_t)u  * 256 + c16 * 8);
            u16x8 B = *(const u16x8*)(Pb + (size_t)vv * 256 + c16 * 8);
#pragma unroll
            for (int jj = 0; jj < 8; ++jj)
                o[jj] = f2b(fmaxf(b2f((unsigned short)A[jj]) + b2f((unsigned short)B[jj]), 0.f));
        }
        int byte = edge * 512 + ((c16 * 16) ^ ((edge & 7) << 4));
        *(u16x8*)((char*)q1 + byte) = o;
    }
    __syncthreads();
    int w = t >> 6, l = t & 63, lr = l & 15, lh = l >> 4;
    f32x4 acc[4][2];
#pragma unroll
    for (int mi = 0; mi < 4; ++mi)
#pragma unroll
        for (int ni = 0; ni < 2; ++ni) { acc[mi][ni][0]=0; acc[mi][ni][1]=0; acc[mi][ni][2]=0; acc[mi][ni][3]=0; }
#pragma unroll
    for (int ks = 0; ks < 8; ++ks) {
        int k0 = ks * 32;
        bf16x8 a[4], wf[2];
#pragma unroll
        for (int mi = 0; mi < 4; ++mi) {
            int row = mi * 16 + lr;
            int byte = row * 512 + ((k0 * 2 + lh * 16) ^ ((row & 7) << 4));
            a[mi] = *(const bf16x8*)((const char*)q1 + byte);
        }
#pragma unroll
        for (int ni = 0; ni < 2; ++ni) {
            int wrow = w * 32 + ni * 16 + lr;
            wf[ni] = *(const bf16x8*)(W2 + (size_t)wrow * 256 + k0 + lh * 8);
        }
#pragma unroll
        for (int mi = 0; mi < 4; ++mi)
#pragma unroll
            for (int ni = 0; ni < 2; ++ni)
                acc[mi][ni] = __builtin_amdgcn_mfma_f32_16x16x32_bf16(a[mi], wf[ni], acc[mi][ni], 0, 0, 0);
    }
    __syncthreads();   // all q1 reads done; safe to overwrite with q2
    {
#pragma unroll
        for (int ni = 0; ni < 2; ++ni) {
            int ch = w * 32 + ni * 16 + lr;
            float sc = g2[ch] * rsqrtf(v2[ch] + FEPS);
            float sh = be2[ch] - m2[ch] * sc;
            float bias = b2[ch];
#pragma unroll
            for (int mi = 0; mi < 4; ++mi)
#pragma unroll
                for (int r = 0; r < 4; ++r) {
                    int row = mi * 16 + lh * 4 + r;
                    float vv = fmaxf((acc[mi][ni][r] + bias) * sc + sh, 0.f);
                    int byte = row * 256 + ((ch * 2) ^ ((row & 7) << 4));
                    *(unsigned short*)((char*)q1 + byte) = f2b(vv);
                }
        }
    }
    __syncthreads();
    {   // layer 3: [64x128] @ W3(128); 4 threads per edge
        int edge = t >> 2, part = t & 3;
        float p = 0.f;
#pragma unroll
        for (int s = 0; s < 4; ++s) {
            int byte = edge * 256 + ((part * 64 + s * 16) ^ ((edge & 7) << 4));
            u16x8 v = *(const u16x8*)((const char*)q1 + byte);
#pragma unroll
            for (int jj = 0; jj < 8; ++jj)
                p += b2f((unsigned short)v[jj]) * W3[part * 32 + s * 8 + jj];
        }
        p += __shfl_xor(p, 1, 64);
        p += __shfl_xor(p, 2, 64);
        int ge = e0 + edge;
        if (part == 0 && ge < NPE) out[ge] = p + b3[0];
    }
}

extern "C" void kernel_launch(void* const* d_in, const int* in_sizes, int n_in,
                              void* d_out, int out_size, void* d_ws, size_t ws_size,
                              hipStream_t stream) {
    const float* x    = (const float*)d_in[0];
    const int*   ei   = (const int*)d_in[1];
    const int*   pei  = (const int*)d_in[2];
    const float* W1l  = (const float*)d_in[3];
    const float* W1r  = (const float*)d_in[4];
    const float* b1   = (const float*)d_in[5];
    const float* bn1g = (const float*)d_in[6];
    const float* bn1b = (const float*)d_in[7];
    const float* bn1m = (const float*)d_in[8];
    const float* bn1v = (const float*)d_in[9];
    const float* W2l  = (const float*)d_in[10];
    const float* W2r  = (const float*)d_in[11];
    const float* b2   = (const float*)d_in[12];
    const float* pW1  = (const float*)d_in[13];
    const float* pb1  = (const float*)d_in[14];
    const float* pg1  = (const float*)d_in[15];
    const float* pbb1 = (const float*)d_in[16];
    const float* pm1  = (const float*)d_in[17];
    const float* pv1  = (const float*)d_in[18];
    const float* pW2  = (const float*)d_in[19];
    const float* pb2  = (const float*)d_in[20];
    const float* pg2  = (const float*)d_in[21];
    const float* pbb2 = (const float*)d_in[22];
    const float* pm2  = (const float*)d_in[23];
    const float* pv2  = (const float*)d_in[24];
    const float* pW3  = (const float*)d_in[25];
    const float* pb3  = (const float*)d_in[26];
    float* out = (float*)d_out;

    const int* src = ei;
    const int* dst = ei + NE;
    const int* pu  = pei;
    const int* pv  = pei + NPE;

    char* p = (char*)d_ws;
    auto alloc = [&](size_t bytes) -> char* {
        char* r = p; p += (bytes + 255) & ~(size_t)255; return r;
    };
    int* cnt    = (int*)alloc((size_t)NN * 4);
    int* cursor = (int*)alloc((size_t)NN * 4);
    int* rowptr = (int*)alloc((size_t)(NN + 1) * 4);
    int* col    = (int*)alloc((size_t)NE * 4);
    unsigned short* xbf  = (unsigned short*)alloc((size_t)NN * 128 * 2);  // -> reused as Pb (first half)
    unsigned short* mx   = (unsigned short*)alloc((size_t)NN * 128 * 2);  // -> reused as Pb (second half)
    unsigned short* hbf  = (unsigned short*)alloc((size_t)NN * 256 * 2);  // -> reused as Pa
    unsigned short* m2b  = (unsigned short*)alloc((size_t)NN * 256 * 2);
    unsigned short* zbf  = (unsigned short*)alloc((size_t)NN * 128 * 2);
    unsigned short* W1lb = (unsigned short*)alloc((size_t)256 * 128 * 2);
    unsigned short* W1rb = (unsigned short*)alloc((size_t)256 * 128 * 2);
    unsigned short* W2lb = (unsigned short*)alloc((size_t)128 * 256 * 2);
    unsigned short* W2rb = (unsigned short*)alloc((size_t)128 * 256 * 2);
    unsigned short* pW1b = (unsigned short*)alloc((size_t)256 * 256 * 2);
    unsigned short* pW2b = (unsigned short*)alloc((size_t)128 * 256 * 2);
    unsigned short* Pa = hbf;   // 25.6 MB, dead after k_sage2
    unsigned short* Pb = xbf;   // xbf+mx contiguous = 25.6 MB, dead after k_sage2

    // zero cnt + cursor (contiguous): 2*200704 bytes = 25088 int4
    k_zero_i<<<98, 256, 0, stream>>>((int4*)cnt, 25088);

    // bf16 conversions
    k_f2b<<<3125, 256, 0, stream>>>(x,   xbf,  NN * 128 / 8);
    k_f2b<<<16,   256, 0, stream>>>(W1l, W1lb, 256 * 128 / 8);
    k_f2b<<<16,   256, 0, stream>>>(W1r, W1rb, 256 * 128 / 8);
    k_f2b<<<16,   256, 0, stream>>>(W2l, W2lb, 128 * 256 / 8);
    k_f2b<<<16,   256, 0, stream>>>(W2r, W2rb, 128 * 256 / 8);
    k_f2b<<<32,   256, 0, stream>>>(pW1, pW1b, 256 * 256 / 8);
    k_f2b<<<16,   256, 0, stream>>>(pW2, pW2b, 128 * 256 / 8);

    // CSR build
    k_hist<<<2500, 256, 0, stream>>>(dst, cnt);
    k_scan<<<1, 1024, 0, stream>>>(cnt, rowptr);
    k_fill<<<2500, 256, 0, stream>>>(src, dst, rowptr, cursor, col);

    // encoder
    k_mean<128><<<12500, 256, 0, stream>>>(xbf, rowptr, col, mx);
    k_sage1<<<782, 256, 0, stream>>>(mx, xbf, W1lb, W1rb, b1, bn1g, bn1b, bn1m, bn1v, hbf);
    k_mean<256><<<12500, 256, 0, stream>>>(hbf, rowptr, col, m2b);
    k_sage2<<<782, 256, 0, stream>>>(m2b, hbf, W2lb, W2rb, b2, zbf);

    // decoder precompute (Pa/Pb overwrite hbf/xbf+mx — dead now)
    k_prep<<<1564, 256, 0, stream>>>(zbf, pW1b, pb1, pg1, pbb1, pm1, pv1, Pa, Pb);

    // fused decoder
    k_mlp<<<(NPE + 63) / 64, 256, 0, stream>>>(Pa, Pb, pu, pv,
                                               pW2b, pb2, pg2, pbb2, pm2, pv2,
                                               pW3, pb3, out);
}

// Round 4
// 400.168 us; speedup vs baseline: 16.9278x; 1.1287x over previous
//
#include <hip/hip_runtime.h>
#include <hip/hip_bf16.h>

#define NN   50000
#define NE   640000
#define NPE  500000
#define FEPS 1e-5f

typedef __attribute__((ext_vector_type(8))) short          bf16x8;
typedef __attribute__((ext_vector_type(8))) unsigned short u16x8;
typedef __attribute__((ext_vector_type(4))) float          f32x4;

__device__ inline float b2f(unsigned short u) {
    union { unsigned int i; float f; } c; c.i = (unsigned int)u << 16; return c.f;
}
__device__ inline unsigned short f2b(float f) {
    __hip_bfloat16 h = __float2bfloat16(f);
    return *reinterpret_cast<unsigned short*>(&h);
}

// ---------------- fused init: zero cnt/cursor + all fp32->bf16 conversions ----------------
// blocks [0,98): zero 25088 int4 ; [98,3223): x ; [3223,3335): weights (contiguous dst)
__global__ __launch_bounds__(256) void k_init(
    int4* __restrict__ zdst,
    const float* __restrict__ x, unsigned short* __restrict__ xbf,
    const float* __restrict__ W1l, const float* __restrict__ W1r,
    const float* __restrict__ W2l, const float* __restrict__ W2r,
    const float* __restrict__ pW1, const float* __restrict__ pW2,
    unsigned short* __restrict__ wdst) {
    int b = blockIdx.x, t = threadIdx.x;
    if (b < 98) {
        int i = b * 256 + t;
        if (i < 25088) zdst[i] = make_int4(0, 0, 0, 0);
        return;
    }
    const float* src;
    unsigned short* dst;
    size_t off;
    if (b < 3223) {
        int i = (b - 98) * 256 + t;
        if (i >= 800000) return;
        src = x; dst = xbf; off = i;
        const float4* p = (const float4*)src + 2 * off;
        float4 a = p[0], c = p[1];
        u16x8 o;
        o[0]=f2b(a.x); o[1]=f2b(a.y); o[2]=f2b(a.z); o[3]=f2b(a.w);
        o[4]=f2b(c.x); o[5]=f2b(c.y); o[6]=f2b(c.z); o[7]=f2b(c.w);
        *((u16x8*)dst + off) = o;
        return;
    }
    int i = (b - 3223) * 256 + t;   // 0..28671
    if (i >= 28672) return;
    if      (i < 4096)  { src = W1l; off = i; }
    else if (i < 8192)  { src = W1r; off = i - 4096; }
    else if (i < 12288) { src = W2l; off = i - 8192; }
    else if (i < 16384) { src = W2r; off = i - 12288; }
    else if (i < 24576) { src = pW1; off = i - 16384; }
    else                { src = pW2; off = i - 24576; }
    const float4* p = (const float4*)src + 2 * off;
    float4 a = p[0], c = p[1];
    u16x8 o;
    o[0]=f2b(a.x); o[1]=f2b(a.y); o[2]=f2b(a.z); o[3]=f2b(a.w);
    o[4]=f2b(c.x); o[5]=f2b(c.y); o[6]=f2b(c.z); o[7]=f2b(c.w);
    *((u16x8*)wdst + i) = o;
}

// ---------------- CSR build ----------------
__global__ void k_hist(const int* __restrict__ dst, int* __restrict__ cnt) {
    int e = blockIdx.x * blockDim.x + threadIdx.x;
    if (e < NE) atomicAdd(&cnt[dst[e]], 1);
}

// parallel 3-phase scan over 50176 padded slots (196 blocks x 256)
__global__ void k_scan1(const int* __restrict__ cnt, int* __restrict__ part) {
    int t = threadIdx.x, lane = t & 63, w = t >> 6;
    int i = blockIdx.x * 256 + t;
    int v = (i < NN) ? cnt[i] : 0;
#pragma unroll
    for (int d = 1; d < 64; d <<= 1) v += __shfl_xor(v, d, 64);
    __shared__ int ws[4];
    if (lane == 0) ws[w] = v;
    __syncthreads();
    if (t == 0) part[blockIdx.x] = ws[0] + ws[1] + ws[2] + ws[3];
}

__global__ void k_scan2(int* __restrict__ part) {   // in-place -> exclusive bases
    int t = threadIdx.x, lane = t & 63, w = t >> 6;
    int v = (t < 196) ? part[t] : 0;
    int s = v;
#pragma unroll
    for (int d = 1; d < 64; d <<= 1) { int u = __shfl_up(s, d, 64); if (lane >= d) s += u; }
    __shared__ int ws[4];
    if (lane == 63) ws[w] = s;
    __syncthreads();
    if (t == 0) { int a = 0; for (int k = 0; k < 4; ++k) { int tmp = ws[k]; ws[k] = a; a += tmp; } }
    __syncthreads();
    if (t < 196) part[t] = ws[w] + s - v;
}

__global__ void k_scan3(const int* __restrict__ cnt, const int* __restrict__ part,
                        int* __restrict__ rowptr) {
    int t = threadIdx.x, lane = t & 63, w = t >> 6;
    int i = blockIdx.x * 256 + t;
    int v = (i < NN) ? cnt[i] : 0;
    int s = v;
#pragma unroll
    for (int d = 1; d < 64; d <<= 1) { int u = __shfl_up(s, d, 64); if (lane >= d) s += u; }
    __shared__ int ws[4];
    if (lane == 63) ws[w] = s;
    __syncthreads();
    if (t == 0) { int a = 0; for (int k = 0; k < 4; ++k) { int tmp = ws[k]; ws[k] = a; a += tmp; } }
    __syncthreads();
    if (i <= NN) rowptr[i] = part[blockIdx.x] + ws[w] + s - v;
}

__global__ void k_fill(const int* __restrict__ src, const int* __restrict__ dst,
                       const int* __restrict__ rowptr, int* __restrict__ cursor,
                       int* __restrict__ col) {
    int e = blockIdx.x * blockDim.x + threadIdx.x;
    if (e >= NE) return;
    int d = dst[e];
    int slot = atomicAdd(&cursor[d], 1);
    col[rowptr[d] + slot] = src[e];
}

// ---------------- gather-mean (CSR), 128-ch rows, 4-deep unrolled ----------------
__global__ __launch_bounds__(256) void k_mean(const unsigned short* __restrict__ feat,
                                              const int* __restrict__ rowptr,
                                              const int* __restrict__ col,
                                              unsigned short* __restrict__ outm) {
    int node = blockIdx.x * 4 + (threadIdx.x >> 6);
    int lane = threadIdx.x & 63;
    if (node >= NN) return;
    int beg = rowptr[node], end = rowptr[node + 1];
    float a0 = 0.f, a1 = 0.f;
    int j = beg;
    for (; j + 4 <= end; j += 4) {
        int s0 = col[j], s1 = col[j + 1], s2 = col[j + 2], s3 = col[j + 3];
        unsigned int v0 = *(const unsigned int*)(feat + (size_t)s0 * 128 + lane * 2);
        unsigned int v1 = *(const unsigned int*)(feat + (size_t)s1 * 128 + lane * 2);
        unsigned int v2 = *(const unsigned int*)(feat + (size_t)s2 * 128 + lane * 2);
        unsigned int v3 = *(const unsigned int*)(feat + (size_t)s3 * 128 + lane * 2);
        a0 += b2f(v0 & 0xffff) + b2f(v1 & 0xffff) + b2f(v2 & 0xffff) + b2f(v3 & 0xffff);
        a1 += b2f(v0 >> 16)    + b2f(v1 >> 16)    + b2f(v2 >> 16)    + b2f(v3 >> 16);
    }
    for (; j < end; ++j) {
        int s = col[j];
        unsigned int v = *(const unsigned int*)(feat + (size_t)s * 128 + lane * 2);
        a0 += b2f(v & 0xffff); a1 += b2f(v >> 16);
    }
    float inv = 1.f / fmaxf((float)(end - beg), 1.f);
    unsigned int v = (unsigned int)f2b(a0 * inv) | ((unsigned int)f2b(a1 * inv) << 16);
    *(unsigned int*)(outm + (size_t)node * 128 + lane * 2) = v;
}

// ---------------- SAGE layer 1 (MFMA): h = relu(bn(mean@Wl^T + x@Wr^T + b)) ----------------
__global__ __launch_bounds__(256) void k_sage1(
    const unsigned short* __restrict__ mean, const unsigned short* __restrict__ self,
    const unsigned short* __restrict__ Wl, const unsigned short* __restrict__ Wr,  // [256][128]
    const float* __restrict__ b, const float* __restrict__ bg, const float* __restrict__ bb,
    const float* __restrict__ bm, const float* __restrict__ bv,
    unsigned short* __restrict__ hout) {  // [NN][256]
    __shared__ unsigned short ms[64 * 128];
    __shared__ unsigned short xs[64 * 128];
    int t = threadIdx.x;
    int n0 = blockIdx.x * 64;
    for (int j = 0; j < 4; ++j) {
        int idx = t + j * 256;
        int row = idx >> 4, c16 = idx & 15;
        int node = n0 + row;
        u16x8 v = {0,0,0,0,0,0,0,0}, v2 = {0,0,0,0,0,0,0,0};
        if (node < NN) {
            v  = *(const u16x8*)(mean + (size_t)node * 128 + c16 * 8);
            v2 = *(const u16x8*)(self + (size_t)node * 128 + c16 * 8);
        }
        int byte = row * 256 + ((c16 * 16) ^ ((row & 7) << 4));
        *(u16x8*)((char*)ms + byte) = v;
        *(u16x8*)((char*)xs + byte) = v2;
    }
    __syncthreads();
    int w = t >> 6, l = t & 63, lr = l & 15, lh = l >> 4;
    f32x4 acc[4][4];
#pragma unroll
    for (int mi = 0; mi < 4; ++mi)
#pragma unroll
        for (int ni = 0; ni < 4; ++ni) { acc[mi][ni][0]=0; acc[mi][ni][1]=0; acc[mi][ni][2]=0; acc[mi][ni][3]=0; }
#pragma unroll
    for (int half = 0; half < 2; ++half) {
        const unsigned short* A = half ? xs : ms;
        const unsigned short* W = half ? Wr : Wl;
#pragma unroll
        for (int ks = 0; ks < 4; ++ks) {
            int k0 = ks * 32;
            bf16x8 a[4], wf[4];
#pragma unroll
            for (int mi = 0; mi < 4; ++mi) {
                int row = mi * 16 + lr;
                int byte = row * 256 + ((k0 * 2 + lh * 16) ^ ((row & 7) << 4));
                a[mi] = *(const bf16x8*)((const char*)A + byte);
            }
#pragma unroll
            for (int ni = 0; ni < 4; ++ni) {
                int wrow = w * 64 + ni * 16 + lr;
                wf[ni] = *(const bf16x8*)(W + (size_t)wrow * 128 + k0 + lh * 8);
            }
#pragma unroll
            for (int mi = 0; mi < 4; ++mi)
#pragma unroll
                for (int ni = 0; ni < 4; ++ni)
                    acc[mi][ni] = __builtin_amdgcn_mfma_f32_16x16x32_bf16(a[mi], wf[ni], acc[mi][ni], 0, 0, 0);
        }
    }
#pragma unroll
    for (int ni = 0; ni < 4; ++ni) {
        int ch = w * 64 + ni * 16 + lr;
        float sc = bg[ch] * rsqrtf(bv[ch] + FEPS);
        float sh = bb[ch] - bm[ch] * sc;
        float bias = b[ch];
#pragma unroll
        for (int mi = 0; mi < 4; ++mi)
#pragma unroll
            for (int r = 0; r < 4; ++r) {
                int node = n0 + mi * 16 + lh * 4 + r;
                if (node < NN) {
                    float vv = (acc[mi][ni][r] + bias) * sc + sh;
                    hout[(size_t)node * 256 + ch] = f2b(fmaxf(vv, 0.f));
                }
            }
    }
}

// ---------------- layer-2 node GEMMs: Y = h@W2l^T ; S = h@W2r^T + b2 ----------------
__global__ __launch_bounds__(256) void k_lin2(
    const unsigned short* __restrict__ h,    // [NN][256]
    const unsigned short* __restrict__ Wl,   // [128][256]
    const unsigned short* __restrict__ Wr,   // [128][256]
    const float* __restrict__ b2,
    unsigned short* __restrict__ Y, unsigned short* __restrict__ S) {
    __shared__ unsigned short hs[64 * 256];
    int t = threadIdx.x;
    int n0 = blockIdx.x * 64;
    for (int j = 0; j < 8; ++j) {
        int idx = t + j * 256;
        int row = idx >> 5, c16 = idx & 31;
        int node = n0 + row;
        u16x8 v = {0,0,0,0,0,0,0,0};
        if (node < NN) v = *(const u16x8*)(h + (size_t)node * 256 + c16 * 8);
        int byte = row * 512 + ((c16 * 16) ^ ((row & 7) << 4));
        *(u16x8*)((char*)hs + byte) = v;
    }
    __syncthreads();
    int w = t >> 6, l = t & 63, lr = l & 15, lh = l >> 4;
    f32x4 aY[4][2], aS[4][2];
#pragma unroll
    for (int mi = 0; mi < 4; ++mi)
#pragma unroll
        for (int ni = 0; ni < 2; ++ni) {
            aY[mi][ni][0]=0; aY[mi][ni][1]=0; aY[mi][ni][2]=0; aY[mi][ni][3]=0;
            aS[mi][ni][0]=0; aS[mi][ni][1]=0; aS[mi][ni][2]=0; aS[mi][ni][3]=0;
        }
#pragma unroll
    for (int ks = 0; ks < 8; ++ks) {
        int k0 = ks * 32;
        bf16x8 a[4], wl[2], wr[2];
#pragma unroll
        for (int mi = 0; mi < 4; ++mi) {
            int row = mi * 16 + lr;
            int byte = row * 512 + ((k0 * 2 + lh * 16) ^ ((row & 7) << 4));
            a[mi] = *(const bf16x8*)((const char*)hs + byte);
        }
#pragma unroll
        for (int ni = 0; ni < 2; ++ni) {
            int wrow = w * 32 + ni * 16 + lr;
            wl[ni] = *(const bf16x8*)(Wl + (size_t)wrow * 256 + k0 + lh * 8);
            wr[ni] = *(const bf16x8*)(Wr + (size_t)wrow * 256 + k0 + lh * 8);
        }
#pragma unroll
        for (int mi = 0; mi < 4; ++mi)
#pragma unroll
            for (int ni = 0; ni < 2; ++ni) {
                aY[mi][ni] = __builtin_amdgcn_mfma_f32_16x16x32_bf16(a[mi], wl[ni], aY[mi][ni], 0, 0, 0);
                aS[mi][ni] = __builtin_amdgcn_mfma_f32_16x16x32_bf16(a[mi], wr[ni], aS[mi][ni], 0, 0, 0);
            }
    }
#pragma unroll
    for (int ni = 0; ni < 2; ++ni) {
        int ch = w * 32 + ni * 16 + lr;
        float bias = b2[ch];
#pragma unroll
        for (int mi = 0; mi < 4; ++mi)
#pragma unroll
            for (int r = 0; r < 4; ++r) {
                int node = n0 + mi * 16 + lh * 4 + r;
                if (node < NN) {
                    Y[(size_t)node * 128 + ch] = f2b(aY[mi][ni][r]);
                    S[(size_t)node * 128 + ch] = f2b(aS[mi][ni][r] + bias);
                }
            }
    }
}

// ---------------- decoder precompute: z=S+mY (on the fly); Pa=(z@W1a^T)*sc1+c1 ; Pb=(z@W1b^T)*sc1 ----------------
__global__ __launch_bounds__(256) void k_prep(
    const unsigned short* __restrict__ S,      // [NN][128]
    const unsigned short* __restrict__ mY,     // [NN][128]
    const unsigned short* __restrict__ W1,     // [256][256] bf16
    const float* __restrict__ b1, const float* __restrict__ g1,
    const float* __restrict__ be1, const float* __restrict__ m1, const float* __restrict__ v1,
    unsigned short* __restrict__ Pa, unsigned short* __restrict__ Pb) {
    __shared__ unsigned short zs[64 * 128];
    int t = threadIdx.x;
    int tile = blockIdx.x >> 1, side = blockIdx.x & 1;
    int n0 = tile * 64;
    for (int j = 0; j < 4; ++j) {
        int idx = t + j * 256;
        int row = idx >> 4, c16 = idx & 15;
        int node = n0 + row;
        u16x8 o = {0,0,0,0,0,0,0,0};
        if (node < NN) {
            u16x8 sv = *(const u16x8*)(S  + (size_t)node * 128 + c16 * 8);
            u16x8 mv = *(const u16x8*)(mY + (size_t)node * 128 + c16 * 8);
#pragma unroll
            for (int jj = 0; jj < 8; ++jj)
                o[jj] = f2b(b2f((unsigned short)sv[jj]) + b2f((unsigned short)mv[jj]));
        }
        int byte = row * 256 + ((c16 * 16) ^ ((row & 7) << 4));
        *(u16x8*)((char*)zs + byte) = o;
    }
    __syncthreads();
    int w = t >> 6, l = t & 63, lr = l & 15, lh = l >> 4;
    f32x4 acc[4][4];
#pragma unroll
    for (int mi = 0; mi < 4; ++mi)
#pragma unroll
        for (int ni = 0; ni < 4; ++ni) { acc[mi][ni][0]=0; acc[mi][ni][1]=0; acc[mi][ni][2]=0; acc[mi][ni][3]=0; }
#pragma unroll
    for (int ks = 0; ks < 4; ++ks) {
        int k0 = ks * 32;
        bf16x8 a[4], wf[4];
#pragma unroll
        for (int mi = 0; mi < 4; ++mi) {
            int row = mi * 16 + lr;
            int byte = row * 256 + ((k0 * 2 + lh * 16) ^ ((row & 7) << 4));
            a[mi] = *(const bf16x8*)((const char*)zs + byte);
        }
#pragma unroll
        for (int ni = 0; ni < 4; ++ni) {
            int ch = w * 64 + ni * 16 + lr;
            wf[ni] = *(const bf16x8*)(W1 + (size_t)ch * 256 + side * 128 + k0 + lh * 8);
        }
#pragma unroll
        for (int mi = 0; mi < 4; ++mi)
#pragma unroll
            for (int ni = 0; ni < 4; ++ni)
                acc[mi][ni] = __builtin_amdgcn_mfma_f32_16x16x32_bf16(a[mi], wf[ni], acc[mi][ni], 0, 0, 0);
    }
    unsigned short* P = side ? Pb : Pa;
#pragma unroll
    for (int ni = 0; ni < 4; ++ni) {
        int ch = w * 64 + ni * 16 + lr;
        float sc = g1[ch] * rsqrtf(v1[ch] + FEPS);
        float add = side ? 0.f : ((b1[ch] - m1[ch]) * sc + be1[ch]);
#pragma unroll
        for (int mi = 0; mi < 4; ++mi)
#pragma unroll
            for (int r = 0; r < 4; ++r) {
                int node = n0 + mi * 16 + lh * 4 + r;
                if (node < NN)
                    P[(size_t)node * 256 + ch] = f2b(acc[mi][ni][r] * sc + add);
            }
    }
}

// ---------------- fused decoder: q1=relu(Pa[u]+Pb[v]); L2 GEMM; L3 dot. 32 edges/block ----------------
__global__ __launch_bounds__(256) void k_mlp(
    const unsigned short* __restrict__ Pa, const unsigned short* __restrict__ Pb,
    const int* __restrict__ pu, const int* __restrict__ pv,
    const unsigned short* __restrict__ W2, const float* __restrict__ b2,
    const float* __restrict__ g2, const float* __restrict__ be2,
    const float* __restrict__ m2, const float* __restrict__ v2,
    const float* __restrict__ W3, const float* __restrict__ b3,
    float* __restrict__ out) {
    __shared__ unsigned short q1[32 * 256];   // 16 KB, reused for q2 after MFMA drain
    int t = threadIdx.x;
    int e0 = blockIdx.x * 32;                 // NPE % 32 == 0, no guards
    for (int j = 0; j < 4; ++j) {
        int idx = t + j * 256;
        int edge = idx >> 5, c16 = idx & 31;
        int ge = e0 + edge;
        int u = pu[ge], vv = pv[ge];
        u16x8 A = *(const u16x8*)(Pa + (size_t)u  * 256 + c16 * 8);
        u16x8 B = *(const u16x8*)(Pb + (size_t)vv * 256 + c16 * 8);
        u16x8 o;
#pragma unroll
        for (int jj = 0; jj < 8; ++jj)
            o[jj] = f2b(fmaxf(b2f((unsigned short)A[jj]) + b2f((unsigned short)B[jj]), 0.f));
        int byte = edge * 512 + ((c16 * 16) ^ ((edge & 7) << 4));
        *(u16x8*)((char*)q1 + byte) = o;
    }
    __syncthreads();
    int w = t >> 6, l = t & 63, lr = l & 15, lh = l >> 4;
    f32x4 acc[2][2];
#pragma unroll
    for (int mi = 0; mi < 2; ++mi)
#pragma unroll
        for (int ni = 0; ni < 2; ++ni) { acc[mi][ni][0]=0; acc[mi][ni][1]=0; acc[mi][ni][2]=0; acc[mi][ni][3]=0; }
#pragma unroll
    for (int ks = 0; ks < 8; ++ks) {
        int k0 = ks * 32;
        bf16x8 a[2], wf[2];
#pragma unroll
        for (int mi = 0; mi < 2; ++mi) {
            int row = mi * 16 + lr;
            int byte = row * 512 + ((k0 * 2 + lh * 16) ^ ((row & 7) << 4));
            a[mi] = *(const bf16x8*)((const char*)q1 + byte);
        }
#pragma unroll
        for (int ni = 0; ni < 2; ++ni) {
            int wrow = w * 32 + ni * 16 + lr;
            wf[ni] = *(const bf16x8*)(W2 + (size_t)wrow * 256 + k0 + lh * 8);
        }
#pragma unroll
        for (int mi = 0; mi < 2; ++mi)
#pragma unroll
            for (int ni = 0; ni < 2; ++ni)
                acc[mi][ni] = __builtin_amdgcn_mfma_f32_16x16x32_bf16(a[mi], wf[ni], acc[mi][ni], 0, 0, 0);
    }
    __syncthreads();   // all q1 reads done; safe to overwrite with q2
#pragma unroll
    for (int ni = 0; ni < 2; ++ni) {
        int ch = w * 32 + ni * 16 + lr;
        float sc = g2[ch] * rsqrtf(v2[ch] + FEPS);
        float sh = be2[ch] - m2[ch] * sc;
        float bias = b2[ch];
#pragma unroll
        for (int mi = 0; mi < 2; ++mi)
#pragma unroll
            for (int r = 0; r < 4; ++r) {
                int row = mi * 16 + lh * 4 + r;
                float vv = fmaxf((acc[mi][ni][r] + bias) * sc + sh, 0.f);
                int byte = row * 256 + ((ch * 2) ^ ((row & 7) << 4));
                *(unsigned short*)((char*)q1 + byte) = f2b(vv);
            }
    }
    __syncthreads();
    {   // layer 3: [32x128] @ W3(128); 8 threads per edge
        int edge = t >> 3, part = t & 7;
        float p = 0.f;
#pragma unroll
        for (int s = 0; s < 2; ++s) {
            int byte = edge * 256 + ((part * 32 + s * 16) ^ ((edge & 7) << 4));
            u16x8 v = *(const u16x8*)((const char*)q1 + byte);
#pragma unroll
            for (int jj = 0; jj < 8; ++jj)
                p += b2f((unsigned short)v[jj]) * W3[part * 16 + s * 8 + jj];
        }
        p += __shfl_xor(p, 1, 64);
        p += __shfl_xor(p, 2, 64);
        p += __shfl_xor(p, 4, 64);
        if (part == 0) out[e0 + edge] = p + b3[0];
    }
}

extern "C" void kernel_launch(void* const* d_in, const int* in_sizes, int n_in,
                              void* d_out, int out_size, void* d_ws, size_t ws_size,
                              hipStream_t stream) {
    const float* x    = (const float*)d_in[0];
    const int*   ei   = (const int*)d_in[1];
    const int*   pei  = (const int*)d_in[2];
    const float* W1l  = (const float*)d_in[3];
    const float* W1r  = (const float*)d_in[4];
    const float* b1   = (const float*)d_in[5];
    const float* bn1g = (const float*)d_in[6];
    const float* bn1b = (const float*)d_in[7];
    const float* bn1m = (const float*)d_in[8];
    const float* bn1v = (const float*)d_in[9];
    const float* W2l  = (const float*)d_in[10];
    const float* W2r  = (const float*)d_in[11];
    const float* b2   = (const float*)d_in[12];
    const float* pW1  = (const float*)d_in[13];
    const float* pb1  = (const float*)d_in[14];
    const float* pg1  = (const float*)d_in[15];
    const float* pbb1 = (const float*)d_in[16];
    const float* pm1  = (const float*)d_in[17];
    const float* pv1  = (const float*)d_in[18];
    const float* pW2  = (const float*)d_in[19];
    const float* pb2  = (const float*)d_in[20];
    const float* pg2  = (const float*)d_in[21];
    const float* pbb2 = (const float*)d_in[22];
    const float* pm2  = (const float*)d_in[23];
    const float* pv2  = (const float*)d_in[24];
    const float* pW3  = (const float*)d_in[25];
    const float* pb3  = (const float*)d_in[26];
    float* out = (float*)d_out;

    const int* src = ei;
    const int* dst = ei + NE;
    const int* pu  = pei;
    const int* pv  = pei + NPE;

    char* p = (char*)d_ws;
    auto alloc = [&](size_t bytes) -> char* {
        char* r = p; p += (bytes + 255) & ~(size_t)255; return r;
    };
    int* cnt    = (int*)alloc((size_t)NN * 4);           // padded to 200704 B
    int* cursor = (int*)alloc((size_t)NN * 4);           // contiguous with cnt
    int* part   = (int*)alloc(256 * 4);
    int* rowptr = (int*)alloc((size_t)(NN + 1) * 4);
    int* col    = (int*)alloc((size_t)NE * 4);
    unsigned short* xbf  = (unsigned short*)alloc((size_t)NN * 128 * 2);  // -> Pb lower half
    unsigned short* mx   = (unsigned short*)alloc((size_t)NN * 128 * 2);  // -> Pb upper half
    unsigned short* hbf  = (unsigned short*)alloc((size_t)NN * 256 * 2);  // -> Pa
    unsigned short* Ybf  = (unsigned short*)alloc((size_t)NN * 128 * 2);
    unsigned short* mY   = (unsigned short*)alloc((size_t)NN * 128 * 2);
    unsigned short* Sbf  = (unsigned short*)alloc((size_t)NN * 128 * 2);
    unsigned short* W1lb = (unsigned short*)alloc((size_t)256 * 128 * 2); // contiguous weight block:
    unsigned short* W1rb = (unsigned short*)alloc((size_t)256 * 128 * 2);
    unsigned short* W2lb = (unsigned short*)alloc((size_t)128 * 256 * 2);
    unsigned short* W2rb = (unsigned short*)alloc((size_t)128 * 256 * 2);
    unsigned short* pW1b = (unsigned short*)alloc((size_t)256 * 256 * 2);
    unsigned short* pW2b = (unsigned short*)alloc((size_t)128 * 256 * 2);
    unsigned short* Pa = hbf;   // [NN][256], overwrites hbf (dead after k_lin2)
    unsigned short* Pb = xbf;   // [NN][256] spanning xbf+mx (dead after k_sage1/k_mean)

    // 1. fused zero + conversions
    k_init<<<3335, 256, 0, stream>>>((int4*)cnt, x, xbf,
                                     W1l, W1r, W2l, W2r, pW1, pW2, W1lb);
    // 2-6. CSR build
    k_hist<<<2500, 256, 0, stream>>>(dst, cnt);
    k_scan1<<<196, 256, 0, stream>>>(cnt, part);
    k_scan2<<<1, 256, 0, stream>>>(part);
    k_scan3<<<196, 256, 0, stream>>>(cnt, part, rowptr);
    k_fill<<<2500, 256, 0, stream>>>(src, dst, rowptr, cursor, col);

    // 7-10. encoder
    k_mean<<<12500, 256, 0, stream>>>(xbf, rowptr, col, mx);
    k_sage1<<<782, 256, 0, stream>>>(mx, xbf, W1lb, W1rb, b1, bn1g, bn1b, bn1m, bn1v, hbf);
    k_lin2<<<782, 256, 0, stream>>>(hbf, W2lb, W2rb, b2, Ybf, Sbf);
    k_mean<<<12500, 256, 0, stream>>>(Ybf, rowptr, col, mY);

    // 11. decoder precompute (Pa/Pb overwrite hbf/xbf+mx — dead now)
    k_prep<<<1564, 256, 0, stream>>>(Sbf, mY, pW1b, pb1, pg1, pbb1, pm1, pv1, Pa, Pb);

    // 12. fused decoder
    k_mlp<<<NPE / 32, 256, 0, stream>>>(Pa, Pb, pu, pv,
                                        pW2b, pb2, pg2, pbb2, pm2, pv2,
                                        pW3, pb3, out);
}

// Round 5
// 374.860 us; speedup vs baseline: 18.0706x; 1.0675x over previous
//
#include <hip/hip_runtime.h>
#include <hip/hip_bf16.h>

#define NN   50000
#define NE   640000
#define NPE  500000
#define FEPS 1e-5f

typedef __attribute__((ext_vector_type(8))) short          bf16x8;
typedef __attribute__((ext_vector_type(8))) unsigned short u16x8;
typedef __attribute__((ext_vector_type(4))) float          f32x4;

__device__ inline float b2f(unsigned short u) {
    union { unsigned int i; float f; } c; c.i = (unsigned int)u << 16; return c.f;
}
__device__ inline unsigned short f2b(float f) {
    __hip_bfloat16 h = __float2bfloat16(f);
    return *reinterpret_cast<unsigned short*>(&h);
}

// ---------------- fused init: zero cnt/cursor + all fp32->bf16 conversions ----------------
// blocks [0,98): zero 25088 int4 ; [98,3223): x ; [3223,3335): weights (contiguous dst)
__global__ __launch_bounds__(256) void k_init(
    int4* __restrict__ zdst,
    const float* __restrict__ x, unsigned short* __restrict__ xbf,
    const float* __restrict__ W1l, const float* __restrict__ W1r,
    const float* __restrict__ W2l, const float* __restrict__ W2r,
    const float* __restrict__ pW1, const float* __restrict__ pW2,
    unsigned short* __restrict__ wdst) {
    int b = blockIdx.x, t = threadIdx.x;
    if (b < 98) {
        int i = b * 256 + t;
        if (i < 25088) zdst[i] = make_int4(0, 0, 0, 0);
        return;
    }
    const float* src;
    unsigned short* dst;
    size_t off;
    if (b < 3223) {
        int i = (b - 98) * 256 + t;
        if (i >= 800000) return;
        src = x; dst = xbf; off = i;
        const float4* p = (const float4*)src + 2 * off;
        float4 a = p[0], c = p[1];
        u16x8 o;
        o[0]=f2b(a.x); o[1]=f2b(a.y); o[2]=f2b(a.z); o[3]=f2b(a.w);
        o[4]=f2b(c.x); o[5]=f2b(c.y); o[6]=f2b(c.z); o[7]=f2b(c.w);
        *((u16x8*)dst + off) = o;
        return;
    }
    int i = (b - 3223) * 256 + t;   // 0..28671
    if (i >= 28672) return;
    if      (i < 4096)  { src = W1l; off = i; }
    else if (i < 8192)  { src = W1r; off = i - 4096; }
    else if (i < 12288) { src = W2l; off = i - 8192; }
    else if (i < 16384) { src = W2r; off = i - 12288; }
    else if (i < 24576) { src = pW1; off = i - 16384; }
    else                { src = pW2; off = i - 24576; }
    const float4* p = (const float4*)src + 2 * off;
    float4 a = p[0], c = p[1];
    u16x8 o;
    o[0]=f2b(a.x); o[1]=f2b(a.y); o[2]=f2b(a.z); o[3]=f2b(a.w);
    o[4]=f2b(c.x); o[5]=f2b(c.y); o[6]=f2b(c.z); o[7]=f2b(c.w);
    *((u16x8*)wdst + i) = o;
}

// ---------------- CSR build ----------------
__global__ void k_hist(const int* __restrict__ dst, int* __restrict__ cnt) {
    int e = blockIdx.x * blockDim.x + threadIdx.x;
    if (e < NE) atomicAdd(&cnt[dst[e]], 1);
}

// parallel 3-phase scan over 50176 padded slots (196 blocks x 256)
__global__ void k_scan1(const int* __restrict__ cnt, int* __restrict__ part) {
    int t = threadIdx.x, lane = t & 63, w = t >> 6;
    int i = blockIdx.x * 256 + t;
    int v = (i < NN) ? cnt[i] : 0;
#pragma unroll
    for (int d = 1; d < 64; d <<= 1) v += __shfl_xor(v, d, 64);
    __shared__ int ws[4];
    if (lane == 0) ws[w] = v;
    __syncthreads();
    if (t == 0) part[blockIdx.x] = ws[0] + ws[1] + ws[2] + ws[3];
}

__global__ void k_scan2(int* __restrict__ part) {   // in-place -> exclusive bases
    int t = threadIdx.x, lane = t & 63, w = t >> 6;
    int v = (t < 196) ? part[t] : 0;
    int s = v;
#pragma unroll
    for (int d = 1; d < 64; d <<= 1) { int u = __shfl_up(s, d, 64); if (lane >= d) s += u; }
    __shared__ int ws[4];
    if (lane == 63) ws[w] = s;
    __syncthreads();
    if (t == 0) { int a = 0; for (int k = 0; k < 4; ++k) { int tmp = ws[k]; ws[k] = a; a += tmp; } }
    __syncthreads();
    if (t < 196) part[t] = ws[w] + s - v;
}

__global__ void k_scan3(const int* __restrict__ cnt, const int* __restrict__ part,
                        int* __restrict__ rowptr) {
    int t = threadIdx.x, lane = t & 63, w = t >> 6;
    int i = blockIdx.x * 256 + t;
    int v = (i < NN) ? cnt[i] : 0;
    int s = v;
#pragma unroll
    for (int d = 1; d < 64; d <<= 1) { int u = __shfl_up(s, d, 64); if (lane >= d) s += u; }
    __shared__ int ws[4];
    if (lane == 63) ws[w] = s;
    __syncthreads();
    if (t == 0) { int a = 0; for (int k = 0; k < 4; ++k) { int tmp = ws[k]; ws[k] = a; a += tmp; } }
    __syncthreads();
    if (i <= NN) rowptr[i] = part[blockIdx.x] + ws[w] + s - v;
}

__global__ void k_fill(const int* __restrict__ src, const int* __restrict__ dst,
                       const int* __restrict__ rowptr, int* __restrict__ cursor,
                       int* __restrict__ col) {
    int e = blockIdx.x * blockDim.x + threadIdx.x;
    if (e >= NE) return;
    int d = dst[e];
    int slot = atomicAdd(&cursor[d], 1);
    col[rowptr[d] + slot] = src[e];
}

// ---------------- gather-mean (CSR), 128-ch rows, 8-deep pipelined ----------------
__global__ __launch_bounds__(256) void k_mean(const unsigned short* __restrict__ feat,
                                              const int* __restrict__ rowptr,
                                              const int* __restrict__ col,
                                              unsigned short* __restrict__ outm) {
    int node = blockIdx.x * 4 + (threadIdx.x >> 6);
    int lane = threadIdx.x & 63;
    if (node >= NN) return;
    int beg = rowptr[node], end = rowptr[node + 1];
    float a0 = 0.f, a1 = 0.f;
    int j = beg;
    for (; j + 8 <= end; j += 8) {
        int s[8];
#pragma unroll
        for (int k = 0; k < 8; ++k) s[k] = col[j + k];
        unsigned int v[8];
#pragma unroll
        for (int k = 0; k < 8; ++k)
            v[k] = *(const unsigned int*)(feat + (size_t)s[k] * 128 + lane * 2);
#pragma unroll
        for (int k = 0; k < 8; ++k) { a0 += b2f(v[k] & 0xffff); a1 += b2f(v[k] >> 16); }
    }
    if (j + 4 <= end) {
        int s[4];
#pragma unroll
        for (int k = 0; k < 4; ++k) s[k] = col[j + k];
        unsigned int v[4];
#pragma unroll
        for (int k = 0; k < 4; ++k)
            v[k] = *(const unsigned int*)(feat + (size_t)s[k] * 128 + lane * 2);
#pragma unroll
        for (int k = 0; k < 4; ++k) { a0 += b2f(v[k] & 0xffff); a1 += b2f(v[k] >> 16); }
        j += 4;
    }
    for (; j < end; ++j) {
        int s = col[j];
        unsigned int v = *(const unsigned int*)(feat + (size_t)s * 128 + lane * 2);
        a0 += b2f(v & 0xffff); a1 += b2f(v >> 16);
    }
    float inv = 1.f / fmaxf((float)(end - beg), 1.f);
    unsigned int v = (unsigned int)f2b(a0 * inv) | ((unsigned int)f2b(a1 * inv) << 16);
    *(unsigned int*)(outm + (size_t)node * 128 + lane * 2) = v;
}

// ---------------- SAGE layer 1 (MFMA): h = relu(bn(mean@Wl^T + x@Wr^T + b)) ----------------
__global__ __launch_bounds__(256) void k_sage1(
    const unsigned short* __restrict__ mean, const unsigned short* __restrict__ self,
    const unsigned short* __restrict__ Wl, const unsigned short* __restrict__ Wr,  // [256][128]
    const float* __restrict__ b, const float* __restrict__ bg, const float* __restrict__ bb,
    const float* __restrict__ bm, const float* __restrict__ bv,
    unsigned short* __restrict__ hout) {  // [NN][256]
    __shared__ unsigned short ms[64 * 128];
    __shared__ unsigned short xs[64 * 128];
    int t = threadIdx.x;
    int n0 = blockIdx.x * 64;
    for (int j = 0; j < 4; ++j) {
        int idx = t + j * 256;
        int row = idx >> 4, c16 = idx & 15;
        int node = n0 + row;
        u16x8 v = {0,0,0,0,0,0,0,0}, v2 = {0,0,0,0,0,0,0,0};
        if (node < NN) {
            v  = *(const u16x8*)(mean + (size_t)node * 128 + c16 * 8);
            v2 = *(const u16x8*)(self + (size_t)node * 128 + c16 * 8);
        }
        int byte = row * 256 + ((c16 * 16) ^ ((row & 7) << 4));
        *(u16x8*)((char*)ms + byte) = v;
        *(u16x8*)((char*)xs + byte) = v2;
    }
    __syncthreads();
    int w = t >> 6, l = t & 63, lr = l & 15, lh = l >> 4;
    f32x4 acc[4][4];
#pragma unroll
    for (int mi = 0; mi < 4; ++mi)
#pragma unroll
        for (int ni = 0; ni < 4; ++ni) { acc[mi][ni][0]=0; acc[mi][ni][1]=0; acc[mi][ni][2]=0; acc[mi][ni][3]=0; }
#pragma unroll
    for (int half = 0; half < 2; ++half) {
        const unsigned short* A = half ? xs : ms;
        const unsigned short* W = half ? Wr : Wl;
#pragma unroll
        for (int ks = 0; ks < 4; ++ks) {
            int k0 = ks * 32;
            bf16x8 a[4], wf[4];
#pragma unroll
            for (int mi = 0; mi < 4; ++mi) {
                int row = mi * 16 + lr;
                int byte = row * 256 + ((k0 * 2 + lh * 16) ^ ((row & 7) << 4));
                a[mi] = *(const bf16x8*)((const char*)A + byte);
            }
#pragma unroll
            for (int ni = 0; ni < 4; ++ni) {
                int wrow = w * 64 + ni * 16 + lr;
                wf[ni] = *(const bf16x8*)(W + (size_t)wrow * 128 + k0 + lh * 8);
            }
#pragma unroll
            for (int mi = 0; mi < 4; ++mi)
#pragma unroll
                for (int ni = 0; ni < 4; ++ni)
                    acc[mi][ni] = __builtin_amdgcn_mfma_f32_16x16x32_bf16(a[mi], wf[ni], acc[mi][ni], 0, 0, 0);
        }
    }
#pragma unroll
    for (int ni = 0; ni < 4; ++ni) {
        int ch = w * 64 + ni * 16 + lr;
        float sc = bg[ch] * rsqrtf(bv[ch] + FEPS);
        float sh = bb[ch] - bm[ch] * sc;
        float bias = b[ch];
#pragma unroll
        for (int mi = 0; mi < 4; ++mi)
#pragma unroll
            for (int r = 0; r < 4; ++r) {
                int node = n0 + mi * 16 + lh * 4 + r;
                if (node < NN) {
                    float vv = (acc[mi][ni][r] + bias) * sc + sh;
                    hout[(size_t)node * 256 + ch] = f2b(fmaxf(vv, 0.f));
                }
            }
    }
}

// ---------------- layer-2 node GEMMs: Y = h@W2l^T ; S = h@W2r^T + b2 ----------------
__global__ __launch_bounds__(256) void k_lin2(
    const unsigned short* __restrict__ h,    // [NN][256]
    const unsigned short* __restrict__ Wl,   // [128][256]
    const unsigned short* __restrict__ Wr,   // [128][256]
    const float* __restrict__ b2,
    unsigned short* __restrict__ Y, unsigned short* __restrict__ S) {
    __shared__ unsigned short hs[64 * 256];
    int t = threadIdx.x;
    int n0 = blockIdx.x * 64;
    for (int j = 0; j < 8; ++j) {
        int idx = t + j * 256;
        int row = idx >> 5, c16 = idx & 31;
        int node = n0 + row;
        u16x8 v = {0,0,0,0,0,0,0,0};
        if (node < NN) v = *(const u16x8*)(h + (size_t)node * 256 + c16 * 8);
        int byte = row * 512 + ((c16 * 16) ^ ((row & 7) << 4));
        *(u16x8*)((char*)hs + byte) = v;
    }
    __syncthreads();
    int w = t >> 6, l = t & 63, lr = l & 15, lh = l >> 4;
    f32x4 aY[4][2], aS[4][2];
#pragma unroll
    for (int mi = 0; mi < 4; ++mi)
#pragma unroll
        for (int ni = 0; ni < 2; ++ni) {
            aY[mi][ni][0]=0; aY[mi][ni][1]=0; aY[mi][ni][2]=0; aY[mi][ni][3]=0;
            aS[mi][ni][0]=0; aS[mi][ni][1]=0; aS[mi][ni][2]=0; aS[mi][ni][3]=0;
        }
#pragma unroll
    for (int ks = 0; ks < 8; ++ks) {
        int k0 = ks * 32;
        bf16x8 a[4], wl[2], wr[2];
#pragma unroll
        for (int mi = 0; mi < 4; ++mi) {
            int row = mi * 16 + lr;
            int byte = row * 512 + ((k0 * 2 + lh * 16) ^ ((row & 7) << 4));
            a[mi] = *(const bf16x8*)((const char*)hs + byte);
        }
#pragma unroll
        for (int ni = 0; ni < 2; ++ni) {
            int wrow = w * 32 + ni * 16 + lr;
            wl[ni] = *(const bf16x8*)(Wl + (size_t)wrow * 256 + k0 + lh * 8);
            wr[ni] = *(const bf16x8*)(Wr + (size_t)wrow * 256 + k0 + lh * 8);
        }
#pragma unroll
        for (int mi = 0; mi < 4; ++mi)
#pragma unroll
            for (int ni = 0; ni < 2; ++ni) {
                aY[mi][ni] = __builtin_amdgcn_mfma_f32_16x16x32_bf16(a[mi], wl[ni], aY[mi][ni], 0, 0, 0);
                aS[mi][ni] = __builtin_amdgcn_mfma_f32_16x16x32_bf16(a[mi], wr[ni], aS[mi][ni], 0, 0, 0);
            }
    }
#pragma unroll
    for (int ni = 0; ni < 2; ++ni) {
        int ch = w * 32 + ni * 16 + lr;
        float bias = b2[ch];
#pragma unroll
        for (int mi = 0; mi < 4; ++mi)
#pragma unroll
            for (int r = 0; r < 4; ++r) {
                int node = n0 + mi * 16 + lh * 4 + r;
                if (node < NN) {
                    Y[(size_t)node * 128 + ch] = f2b(aY[mi][ni][r]);
                    S[(size_t)node * 128 + ch] = f2b(aS[mi][ni][r] + bias);
                }
            }
    }
}

// ---------------- decoder precompute: z=S+mY (on the fly); Pa=(z@W1a^T)*sc1+c1 ; Pb=(z@W1b^T)*sc1 ----------------
__global__ __launch_bounds__(256) void k_prep(
    const unsigned short* __restrict__ S,      // [NN][128]
    const unsigned short* __restrict__ mY,     // [NN][128]
    const unsigned short* __restrict__ W1,     // [256][256] bf16
    const float* __restrict__ b1, const float* __restrict__ g1,
    const float* __restrict__ be1, const float* __restrict__ m1, const float* __restrict__ v1,
    unsigned short* __restrict__ Pa, unsigned short* __restrict__ Pb) {
    __shared__ unsigned short zs[64 * 128];
    int t = threadIdx.x;
    int tile = blockIdx.x >> 1, side = blockIdx.x & 1;
    int n0 = tile * 64;
    for (int j = 0; j < 4; ++j) {
        int idx = t + j * 256;
        int row = idx >> 4, c16 = idx & 15;
        int node = n0 + row;
        u16x8 o = {0,0,0,0,0,0,0,0};
        if (node < NN) {
            u16x8 sv = *(const u16x8*)(S  + (size_t)node * 128 + c16 * 8);
            u16x8 mv = *(const u16x8*)(mY + (size_t)node * 128 + c16 * 8);
#pragma unroll
            for (int jj = 0; jj < 8; ++jj)
                o[jj] = f2b(b2f((unsigned short)sv[jj]) + b2f((unsigned short)mv[jj]));
        }
        int byte = row * 256 + ((c16 * 16) ^ ((row & 7) << 4));
        *(u16x8*)((char*)zs + byte) = o;
    }
    __syncthreads();
    int w = t >> 6, l = t & 63, lr = l & 15, lh = l >> 4;
    f32x4 acc[4][4];
#pragma unroll
    for (int mi = 0; mi < 4; ++mi)
#pragma unroll
        for (int ni = 0; ni < 4; ++ni) { acc[mi][ni][0]=0; acc[mi][ni][1]=0; acc[mi][ni][2]=0; acc[mi][ni][3]=0; }
#pragma unroll
    for (int ks = 0; ks < 4; ++ks) {
        int k0 = ks * 32;
        bf16x8 a[4], wf[4];
#pragma unroll
        for (int mi = 0; mi < 4; ++mi) {
            int row = mi * 16 + lr;
            int byte = row * 256 + ((k0 * 2 + lh * 16) ^ ((row & 7) << 4));
            a[mi] = *(const bf16x8*)((const char*)zs + byte);
        }
#pragma unroll
        for (int ni = 0; ni < 4; ++ni) {
            int ch = w * 64 + ni * 16 + lr;
            wf[ni] = *(const bf16x8*)(W1 + (size_t)ch * 256 + side * 128 + k0 + lh * 8);
        }
#pragma unroll
        for (int mi = 0; mi < 4; ++mi)
#pragma unroll
            for (int ni = 0; ni < 4; ++ni)
                acc[mi][ni] = __builtin_amdgcn_mfma_f32_16x16x32_bf16(a[mi], wf[ni], acc[mi][ni], 0, 0, 0);
    }
    unsigned short* P = side ? Pb : Pa;
#pragma unroll
    for (int ni = 0; ni < 4; ++ni) {
        int ch = w * 64 + ni * 16 + lr;
        float sc = g1[ch] * rsqrtf(v1[ch] + FEPS);
        float add = side ? 0.f : ((b1[ch] - m1[ch]) * sc + be1[ch]);
#pragma unroll
        for (int mi = 0; mi < 4; ++mi)
#pragma unroll
            for (int r = 0; r < 4; ++r) {
                int node = n0 + mi * 16 + lh * 4 + r;
                if (node < NN)
                    P[(size_t)node * 256 + ch] = f2b(acc[mi][ni][r] * sc + add);
            }
    }
}

// ---------------- fused decoder: q1=relu(Pa[u]+Pb[v]); L2 GEMM; L3 dot. 64 edges/block ----------------
// gathers batch-issued (4 row-pairs in flight per lane) to maximize memory-level parallelism
__global__ __launch_bounds__(256, 5) void k_mlp(
    const unsigned short* __restrict__ Pa, const unsigned short* __restrict__ Pb,
    const int* __restrict__ pu, const int* __restrict__ pv,
    const unsigned short* __restrict__ W2, const float* __restrict__ b2,
    const float* __restrict__ g2, const float* __restrict__ be2,
    const float* __restrict__ m2, const float* __restrict__ v2,
    const float* __restrict__ W3, const float* __restrict__ b3,
    float* __restrict__ out) {
    __shared__ unsigned short q1[64 * 256];   // 32 KB, reused for q2 after MFMA drain
    int t = threadIdx.x;
    int e0 = blockIdx.x * 64;
#pragma unroll
    for (int batch = 0; batch < 2; ++batch) {
        u16x8 A[4], B[4];
        int bofs[4];
        // issue all 8 gather loads of this batch before any consume
#pragma unroll
        for (int j = 0; j < 4; ++j) {
            int idx = t + (batch * 4 + j) * 256;
            int edge = idx >> 5, c16 = idx & 31;
            int ge = e0 + edge;
            if (ge < NPE) {
                int u = pu[ge], vv = pv[ge];
                A[j] = *(const u16x8*)(Pa + (size_t)u  * 256 + c16 * 8);
                B[j] = *(const u16x8*)(Pb + (size_t)vv * 256 + c16 * 8);
            } else {
                A[j] = (u16x8){0,0,0,0,0,0,0,0};
                B[j] = (u16x8){0,0,0,0,0,0,0,0};
            }
            bofs[j] = edge * 512 + ((c16 * 16) ^ ((edge & 7) << 4));
        }
#pragma unroll
        for (int j = 0; j < 4; ++j) {
            u16x8 o;
#pragma unroll
            for (int jj = 0; jj < 8; ++jj)
                o[jj] = f2b(fmaxf(b2f((unsigned short)A[j][jj]) + b2f((unsigned short)B[j][jj]), 0.f));
            *(u16x8*)((char*)q1 + bofs[j]) = o;
        }
    }
    __syncthreads();
    int w = t >> 6, l = t & 63, lr = l & 15, lh = l >> 4;
    f32x4 acc[4][2];
#pragma unroll
    for (int mi = 0; mi < 4; ++mi)
#pragma unroll
        for (int ni = 0; ni < 2; ++ni) { acc[mi][ni][0]=0; acc[mi][ni][1]=0; acc[mi][ni][2]=0; acc[mi][ni][3]=0; }
#pragma unroll
    for (int ks = 0; ks < 8; ++ks) {
        int k0 = ks * 32;
        bf16x8 a[4], wf[2];
#pragma unroll
        for (int mi = 0; mi < 4; ++mi) {
            int row = mi * 16 + lr;
            int byte = row * 512 + ((k0 * 2 + lh * 16) ^ ((row & 7) << 4));
            a[mi] = *(const bf16x8*)((const char*)q1 + byte);
        }
#pragma unroll
        for (int ni = 0; ni < 2; ++ni) {
            int wrow = w * 32 + ni * 16 + lr;
            wf[ni] = *(const bf16x8*)(W2 + (size_t)wrow * 256 + k0 + lh * 8);
        }
#pragma unroll
        for (int mi = 0; mi < 4; ++mi)
#pragma unroll
            for (int ni = 0; ni < 2; ++ni)
                acc[mi][ni] = __builtin_amdgcn_mfma_f32_16x16x32_bf16(a[mi], wf[ni], acc[mi][ni], 0, 0, 0);
    }
    __syncthreads();   // all q1 reads done; safe to overwrite with q2
#pragma unroll
    for (int ni = 0; ni < 2; ++ni) {
        int ch = w * 32 + ni * 16 + lr;
        float sc = g2[ch] * rsqrtf(v2[ch] + FEPS);
        float sh = be2[ch] - m2[ch] * sc;
        float bias = b2[ch];
#pragma unroll
        for (int mi = 0; mi < 4; ++mi)
#pragma unroll
            for (int r = 0; r < 4; ++r) {
                int row = mi * 16 + lh * 4 + r;
                float vv = fmaxf((acc[mi][ni][r] + bias) * sc + sh, 0.f);
                int byte = row * 256 + ((ch * 2) ^ ((row & 7) << 4));
                *(unsigned short*)((char*)q1 + byte) = f2b(vv);
            }
    }
    __syncthreads();
    {   // layer 3: [64x128] @ W3(128); 4 threads per edge
        int edge = t >> 2, part = t & 3;
        float p = 0.f;
#pragma unroll
        for (int s = 0; s < 4; ++s) {
            int byte = edge * 256 + ((part * 64 + s * 16) ^ ((edge & 7) << 4));
            u16x8 v = *(const u16x8*)((const char*)q1 + byte);
#pragma unroll
            for (int jj = 0; jj < 8; ++jj)
                p += b2f((unsigned short)v[jj]) * W3[part * 32 + s * 8 + jj];
        }
        p += __shfl_xor(p, 1, 64);
        p += __shfl_xor(p, 2, 64);
        int ge = e0 + edge;
        if (part == 0 && ge < NPE) out[ge] = p + b3[0];
    }
}

extern "C" void kernel_launch(void* const* d_in, const int* in_sizes, int n_in,
                              void* d_out, int out_size, void* d_ws, size_t ws_size,
                              hipStream_t stream) {
    const float* x    = (const float*)d_in[0];
    const int*   ei   = (const int*)d_in[1];
    const int*   pei  = (const int*)d_in[2];
    const float* W1l  = (const float*)d_in[3];
    const float* W1r  = (const float*)d_in[4];
    const float* b1   = (const float*)d_in[5];
    const float* bn1g = (const float*)d_in[6];
    const float* bn1b = (const float*)d_in[7];
    const float* bn1m = (const float*)d_in[8];
    const float* bn1v = (const float*)d_in[9];
    const float* W2l  = (const float*)d_in[10];
    const float* W2r  = (const float*)d_in[11];
    const float* b2   = (const float*)d_in[12];
    const float* pW1  = (const float*)d_in[13];
    const float* pb1  = (const float*)d_in[14];
    const float* pg1  = (const float*)d_in[15];
    const float* pbb1 = (const float*)d_in[16];
    const float* pm1  = (const float*)d_in[17];
    const float* pv1  = (const float*)d_in[18];
    const float* pW2  = (const float*)d_in[19];
    const float* pb2  = (const float*)d_in[20];
    const float* pg2  = (const float*)d_in[21];
    const float* pbb2 = (const float*)d_in[22];
    const float* pm2  = (const float*)d_in[23];
    const float* pv2  = (const float*)d_in[24];
    const float* pW3  = (const float*)d_in[25];
    const float* pb3  = (const float*)d_in[26];
    float* out = (float*)d_out;

    const int* src = ei;
    const int* dst = ei + NE;
    const int* pu  = pei;
    const int* pv  = pei + NPE;

    char* p = (char*)d_ws;
    auto alloc = [&](size_t bytes) -> char* {
        char* r = p; p += (bytes + 255) & ~(size_t)255; return r;
    };
    int* cnt    = (int*)alloc((size_t)NN * 4);           // padded to 200704 B
    int* cursor = (int*)alloc((size_t)NN * 4);           // contiguous with cnt
    int* part   = (int*)alloc(256 * 4);
    int* rowptr = (int*)alloc((size_t)(NN + 1) * 4);
    int* col    = (int*)alloc((size_t)NE * 4);
    unsigned short* xbf  = (unsigned short*)alloc((size_t)NN * 128 * 2);  // -> Pb lower half
    unsigned short* mx   = (unsigned short*)alloc((size_t)NN * 128 * 2);  // -> Pb upper half
    unsigned short* hbf  = (unsigned short*)alloc((size_t)NN * 256 * 2);  // -> Pa
    unsigned short* Ybf  = (unsigned short*)alloc((size_t)NN * 128 * 2);
    unsigned short* mY   = (unsigned short*)alloc((size_t)NN * 128 * 2);
    unsigned short* Sbf  = (unsigned short*)alloc((size_t)NN * 128 * 2);
    unsigned short* W1lb = (unsigned short*)alloc((size_t)256 * 128 * 2); // contiguous weight block:
    unsigned short* W1rb = (unsigned short*)alloc((size_t)256 * 128 * 2);
    unsigned short* W2lb = (unsigned short*)alloc((size_t)128 * 256 * 2);
    unsigned short* W2rb = (unsigned short*)alloc((size_t)128 * 256 * 2);
    unsigned short* pW1b = (unsigned short*)alloc((size_t)256 * 256 * 2);
    unsigned short* pW2b = (unsigned short*)alloc((size_t)128 * 256 * 2);
    unsigned short* Pa = hbf;   // [NN][256], overwrites hbf (dead after k_lin2)
    unsigned short* Pb = xbf;   // [NN][256] spanning xbf+mx (dead after k_sage1/k_mean)

    // 1. fused zero + conversions
    k_init<<<3335, 256, 0, stream>>>((int4*)cnt, x, xbf,
                                     W1l, W1r, W2l, W2r, pW1, pW2, W1lb);
    // 2-6. CSR build
    k_hist<<<2500, 256, 0, stream>>>(dst, cnt);
    k_scan1<<<196, 256, 0, stream>>>(cnt, part);
    k_scan2<<<1, 256, 0, stream>>>(part);
    k_scan3<<<196, 256, 0, stream>>>(cnt, part, rowptr);
    k_fill<<<2500, 256, 0, stream>>>(src, dst, rowptr, cursor, col);

    // 7-10. encoder
    k_mean<<<12500, 256, 0, stream>>>(xbf, rowptr, col, mx);
    k_sage1<<<782, 256, 0, stream>>>(mx, xbf, W1lb, W1rb, b1, bn1g, bn1b, bn1m, bn1v, hbf);
    k_lin2<<<782, 256, 0, stream>>>(hbf, W2lb, W2rb, b2, Ybf, Sbf);
    k_mean<<<12500, 256, 0, stream>>>(Ybf, rowptr, col, mY);

    // 11. decoder precompute (Pa/Pb overwrite hbf/xbf+mx — dead now)
    k_prep<<<1564, 256, 0, stream>>>(Sbf, mY, pW1b, pb1, pg1, pbb1, pm1, pv1, Pa, Pb);

    // 12. fused decoder
    k_mlp<<<(NPE + 63) / 64, 256, 0, stream>>>(Pa, Pb, pu, pv,
                                               pW2b, pb2, pg2, pbb2, pm2, pv2,
                                               pW3, pb3, out);
}